// Round 1
// baseline (1192.858 us; speedup 1.0000x reference)
//
#include <hip/hip_runtime.h>
#include <math.h>

#define NEG_SLOPE 0.2f
#define BN_EPS 1e-5f

__device__ __forceinline__ float wave_sum(float v) {
  #pragma unroll
  for (int off = 32; off > 0; off >>= 1) v += __shfl_xor(v, off, 64);
  return v;
}

// ---------------- utility ----------------
__global__ void k_zero_i32(int* __restrict__ p, int n) {
  int i = blockIdx.x * blockDim.x + threadIdx.x;
  if (i < n) p[i] = 0;
}

// ---------------- CSR build (group edges by dst) ----------------
// edge list = edge_index[0][e]=src, edge_index[1][e]=dst for e<E, plus N self-loops.
__global__ void k_count(const int* __restrict__ ei, int E, int N, int* __restrict__ deg) {
  int e = blockIdx.x * blockDim.x + threadIdx.x;
  int T = E + N;
  if (e >= T) return;
  int d = (e < E) ? ei[E + e] : (e - E);
  atomicAdd(&deg[d], 1);
}

// single-block exclusive scan (1024 threads, wave-shuffle based)
__global__ __launch_bounds__(1024) void k_scan(const int* __restrict__ deg, int N,
                                               int* __restrict__ offs, int* __restrict__ cursor) {
  __shared__ int wsum[16];
  __shared__ int s_base;
  int t = threadIdx.x;
  int lane = t & 63, w = t >> 6;
  if (t == 0) s_base = 0;
  __syncthreads();
  for (int start = 0; start < N; start += 1024) {
    int i = start + t;
    int v = (i < N) ? deg[i] : 0;
    int val = v;
    #pragma unroll
    for (int off = 1; off < 64; off <<= 1) {
      int x = __shfl_up(val, off, 64);
      if (lane >= off) val += x;
    }
    if (lane == 63) wsum[w] = val;
    __syncthreads();
    if (w == 0) {
      int s = (lane < 16) ? wsum[lane] : 0;
      #pragma unroll
      for (int off = 1; off < 16; off <<= 1) {
        int x = __shfl_up(s, off, 64);
        if (lane >= off) s += x;
      }
      if (lane < 16) wsum[lane] = s;
    }
    __syncthreads();
    int base = s_base;
    int woff = (w > 0) ? wsum[w - 1] : 0;
    int excl = base + woff + (val - v);
    if (i < N) { offs[i] = excl; cursor[i] = excl; }
    int total = wsum[15];
    __syncthreads();
    if (t == 0) s_base = base + total;
    __syncthreads();
  }
  if (t == 0) offs[N] = s_base;
}

__global__ void k_scatter(const int* __restrict__ ei, int E, int N,
                          int* __restrict__ cursor, int* __restrict__ csr_src) {
  int e = blockIdx.x * blockDim.x + threadIdx.x;
  int T = E + N;
  if (e >= T) return;
  int s, d;
  if (e < E) { s = ei[e]; d = ei[E + e]; } else { s = d = e - E; }
  int pos = atomicAdd(&cursor[d], 1);
  csr_src[pos] = s;
}

// ---------------- fp32 tiled GEMM: C[M,N] = A[M,K] @ B[K,N] ----------------
#define BM 64
#define BN 64
#define BK 16
__global__ __launch_bounds__(256) void k_sgemm(const float* __restrict__ A, const float* __restrict__ B,
                                               float* __restrict__ C, int M, int N, int K) {
  __shared__ float As[BK][BM];
  __shared__ float Bs[BK][BN];
  int t = threadIdx.x;
  int tx = t & 15, ty = t >> 4;
  int bm0 = blockIdx.x * BM, bn0 = blockIdx.y * BN;
  float acc[4][4] = {};
  for (int k0 = 0; k0 < K; k0 += BK) {
    int li = t * 4;
    int ar = li / BK, ac = li % BK;          // A tile: BM x BK
    int arow = bm0 + ar;
    float4 av = make_float4(0.f, 0.f, 0.f, 0.f);
    if (arow < M) av = *reinterpret_cast<const float4*>(&A[(size_t)arow * K + k0 + ac]);
    As[ac + 0][ar] = av.x; As[ac + 1][ar] = av.y; As[ac + 2][ar] = av.z; As[ac + 3][ar] = av.w;
    int br = li / BN, bc = li % BN;          // B tile: BK x BN
    float4 bv = *reinterpret_cast<const float4*>(&B[(size_t)(k0 + br) * N + bn0 + bc]);
    *reinterpret_cast<float4*>(&Bs[br][bc]) = bv;
    __syncthreads();
    #pragma unroll
    for (int kk = 0; kk < BK; ++kk) {
      float a[4], b[4];
      #pragma unroll
      for (int i = 0; i < 4; ++i) a[i] = As[kk][ty * 4 + i];
      #pragma unroll
      for (int j = 0; j < 4; ++j) b[j] = Bs[kk][tx * 4 + j];
      #pragma unroll
      for (int i = 0; i < 4; ++i)
        #pragma unroll
        for (int j = 0; j < 4; ++j) acc[i][j] += a[i] * b[j];
    }
    __syncthreads();
  }
  #pragma unroll
  for (int i = 0; i < 4; ++i) {
    int row = bm0 + ty * 4 + i;
    if (row >= M) break;
    #pragma unroll
    for (int j = 0; j < 4; ++j) C[(size_t)row * N + bn0 + tx * 4 + j] = acc[i][j];
  }
}

// ---------------- fused GATv2 edge phase, H=4, F=64 (Hm=256) ----------------
// 1 block / node, 256 threads; wave w = head h, lane = f. Online softmax.
__global__ __launch_bounds__(256) void k_gat4(const float* __restrict__ xl, const float* __restrict__ xr,
                                              const float* __restrict__ att, const float* __restrict__ bias,
                                              const float* __restrict__ g, const float* __restrict__ bb,
                                              const float* __restrict__ rm, const float* __restrict__ rv,
                                              const int* __restrict__ offs, const int* __restrict__ csr,
                                              float* __restrict__ out) {
  int n = blockIdx.x;
  int t = threadIdx.x;
  float xr_t = xr[(size_t)n * 256 + t];
  float att_t = att[t];
  int j0 = offs[n], j1 = offs[n + 1];
  float m = -INFINITY, l = 0.f, acc = 0.f;
  for (int j = j0; j < j1; ++j) {
    int s = csr[j];
    float v = xl[(size_t)s * 256 + t];
    float sv = v + xr_t;
    sv = sv > 0.f ? sv : NEG_SLOPE * sv;
    float e = wave_sum(sv * att_t);
    float mn = fmaxf(m, e);
    float c = __expf(m - mn);
    float pe = __expf(e - mn);
    l = l * c + pe;
    acc = acc * c + pe * v;
    m = mn;
  }
  float o = acc / l + bias[t];
  o = (o - rm[t]) * rsqrtf(rv[t] + BN_EPS) * g[t] + bb[t];
  o = o > 0.f ? o : (__expf(o) - 1.f);   // ELU
  out[(size_t)n * 256 + t] = o;
}

// ---------------- fused GATv2 edge phase, H=1, F=128 (layer 3) ----------------
// 1 block / node, 64 threads; each lane owns channels t and t+64.
__global__ __launch_bounds__(64) void k_gat1(const float* __restrict__ xl, const float* __restrict__ xr,
                                             const float* __restrict__ att, const float* __restrict__ bias,
                                             const int* __restrict__ offs, const int* __restrict__ csr,
                                             float* __restrict__ out) {
  int n = blockIdx.x;
  int t = threadIdx.x;
  float xr0 = xr[(size_t)n * 128 + t];
  float xr1 = xr[(size_t)n * 128 + t + 64];
  float a0 = att[t], a1 = att[t + 64];
  int j0 = offs[n], j1 = offs[n + 1];
  float m = -INFINITY, l = 0.f, acc0 = 0.f, acc1 = 0.f;
  for (int j = j0; j < j1; ++j) {
    int s = csr[j];
    float v0 = xl[(size_t)s * 128 + t];
    float v1 = xl[(size_t)s * 128 + t + 64];
    float s0 = v0 + xr0; s0 = s0 > 0.f ? s0 : NEG_SLOPE * s0;
    float s1 = v1 + xr1; s1 = s1 > 0.f ? s1 : NEG_SLOPE * s1;
    float e = wave_sum(s0 * a0 + s1 * a1);
    float mn = fmaxf(m, e);
    float c = __expf(m - mn);
    float pe = __expf(e - mn);
    l = l * c + pe;
    acc0 = acc0 * c + pe * v0;
    acc1 = acc1 * c + pe * v1;
    m = mn;
  }
  out[(size_t)n * 128 + t] = acc0 / l + bias[t];
  out[(size_t)n * 128 + t + 64] = acc1 / l + bias[t + 64];
}

extern "C" void kernel_launch(void* const* d_in, const int* in_sizes, int n_in,
                              void* d_out, int out_size, void* d_ws, size_t ws_size,
                              hipStream_t stream) {
  const float* x    = (const float*)d_in[0];
  const int*   ei   = (const int*)d_in[1];
  const float* Wl1  = (const float*)d_in[2];
  const float* Wr1  = (const float*)d_in[3];
  const float* att1 = (const float*)d_in[4];
  const float* b1   = (const float*)d_in[5];
  const float* bn1g = (const float*)d_in[6];
  const float* bn1b = (const float*)d_in[7];
  const float* bn1m = (const float*)d_in[8];
  const float* bn1v = (const float*)d_in[9];
  const float* Wl2  = (const float*)d_in[10];
  const float* Wr2  = (const float*)d_in[11];
  const float* att2 = (const float*)d_in[12];
  const float* b2   = (const float*)d_in[13];
  const float* bn2g = (const float*)d_in[14];
  const float* bn2b = (const float*)d_in[15];
  const float* bn2m = (const float*)d_in[16];
  const float* bn2v = (const float*)d_in[17];
  const float* Wl3  = (const float*)d_in[18];
  const float* Wr3  = (const float*)d_in[19];
  const float* att3 = (const float*)d_in[20];
  const float* b3   = (const float*)d_in[21];

  const int Hm   = in_sizes[5];          // 256
  const int Cout = in_sizes[21];         // 128
  const int Cin  = in_sizes[2] / Hm;     // 128
  const int N    = in_sizes[0] / Cin;    // 50000
  const int E    = in_sizes[1] / 2;      // 800000
  const int T    = E + N;                // edges incl. self-loops

  float* ws = (float*)d_ws;
  size_t nHm = (size_t)N * Hm;
  float* xl = ws;                 // N*Hm
  float* xr = xl + nHm;           // N*Hm
  float* h  = xr + nHm;           // N*Hm
  int* deg    = (int*)(h + nHm);  // N
  int* offs   = deg + N;          // N+1
  int* cursor = offs + N + 1;     // N
  int* csr    = cursor + N;       // T

  // --- build CSR by dst (every call; deterministic up to fp-order) ---
  k_zero_i32<<<(N + 255) / 256, 256, 0, stream>>>(deg, N);
  k_count<<<(T + 255) / 256, 256, 0, stream>>>(ei, E, N, deg);
  k_scan<<<1, 1024, 0, stream>>>(deg, N, offs, cursor);
  k_scatter<<<(T + 255) / 256, 256, 0, stream>>>(ei, E, N, cursor, csr);

  dim3 gemm_grid((N + BM - 1) / BM, Hm / BN);
  dim3 gemm_grid3((N + BM - 1) / BM, Cout / BN);

  // --- layer 1 ---
  k_sgemm<<<gemm_grid, 256, 0, stream>>>(x, Wl1, xl, N, Hm, Cin);
  k_sgemm<<<gemm_grid, 256, 0, stream>>>(x, Wr1, xr, N, Hm, Cin);
  k_gat4<<<N, 256, 0, stream>>>(xl, xr, att1, b1, bn1g, bn1b, bn1m, bn1v, offs, csr, h);

  // --- layer 2 ---
  k_sgemm<<<gemm_grid, 256, 0, stream>>>(h, Wl2, xl, N, Hm, Hm);
  k_sgemm<<<gemm_grid, 256, 0, stream>>>(h, Wr2, xr, N, Hm, Hm);
  k_gat4<<<N, 256, 0, stream>>>(xl, xr, att2, b2, bn2g, bn2b, bn2m, bn2v, offs, csr, h);

  // --- layer 3 (H=1, F=128, no BN/ELU, mean over 1 head = identity) ---
  k_sgemm<<<gemm_grid3, 256, 0, stream>>>(h, Wl3, xl, N, Cout, Hm);
  k_sgemm<<<gemm_grid3, 256, 0, stream>>>(h, Wr3, xr, N, Cout, Hm);
  k_gat1<<<N, 64, 0, stream>>>(xl, xr, att3, b3, offs, csr, (float*)d_out);
}

// Round 2
// 583.657 us; speedup vs baseline: 2.0438x; 2.0438x over previous
//
#include <hip/hip_runtime.h>
#include <math.h>

#define NEG_SLOPE 0.2f
#define BN_EPS 1e-5f

typedef _Float16 f16x8 __attribute__((ext_vector_type(8)));
typedef float f32x4 __attribute__((ext_vector_type(4)));

__device__ __forceinline__ void async_copy16(const void* g, void* l) {
  __builtin_amdgcn_global_load_lds(
      (const __attribute__((address_space(1))) void*)g,
      (__attribute__((address_space(3))) void*)l, 16, 0, 0);
}

__device__ __forceinline__ float2 unpack2(unsigned int u) {
  union { unsigned int u; _Float16 h[2]; } c; c.u = u;
  return make_float2((float)c.h[0], (float)c.h[1]);
}
__device__ __forceinline__ unsigned int pack2(float a, float b) {
  union { unsigned int u; _Float16 h[2]; } c;
  c.h[0] = (_Float16)a; c.h[1] = (_Float16)b; return c.u;
}

// ---------------- utility ----------------
__global__ void k_zero_i32(int* __restrict__ p, int n) {
  int i = blockIdx.x * blockDim.x + threadIdx.x;
  if (i < n) p[i] = 0;
}

__global__ void k_f2h(const float* __restrict__ in, unsigned int* __restrict__ out, int n2) {
  int i = blockIdx.x * blockDim.x + threadIdx.x;
  if (i < n2) {
    float2 v = reinterpret_cast<const float2*>(in)[i];
    out[i] = pack2(v.x, v.y);
  }
}

// WT[c][k] = (c<Ch ? Wl[k][c] : Wr[k][c-Ch]) as fp16; WT is [2*Ch][K]
__global__ void k_prep_w(const float* __restrict__ Wl, const float* __restrict__ Wr,
                         int K, int Ch, _Float16* __restrict__ WT) {
  int i = blockIdx.x * blockDim.x + threadIdx.x;
  int total = 2 * Ch * K;
  if (i >= total) return;
  int c = i / K, k = i % K;
  float v = (c < Ch) ? Wl[(size_t)k * Ch + c] : Wr[(size_t)k * Ch + (c - Ch)];
  WT[i] = (_Float16)v;
}

// ---------------- CSR build (group edges by dst) ----------------
__global__ void k_count(const int* __restrict__ ei, int E, int N, int* __restrict__ deg) {
  int e = blockIdx.x * blockDim.x + threadIdx.x;
  int T = E + N;
  if (e >= T) return;
  int d = (e < E) ? ei[E + e] : (e - E);
  atomicAdd(&deg[d], 1);
}

__global__ __launch_bounds__(1024) void k_scan(const int* __restrict__ deg, int N,
                                               int* __restrict__ offs, int* __restrict__ cursor) {
  __shared__ int wsum[16];
  __shared__ int s_base;
  int t = threadIdx.x;
  int lane = t & 63, w = t >> 6;
  if (t == 0) s_base = 0;
  __syncthreads();
  for (int start = 0; start < N; start += 1024) {
    int i = start + t;
    int v = (i < N) ? deg[i] : 0;
    int val = v;
    #pragma unroll
    for (int off = 1; off < 64; off <<= 1) {
      int x = __shfl_up(val, off, 64);
      if (lane >= off) val += x;
    }
    if (lane == 63) wsum[w] = val;
    __syncthreads();
    if (w == 0) {
      int s = (lane < 16) ? wsum[lane] : 0;
      #pragma unroll
      for (int off = 1; off < 16; off <<= 1) {
        int x = __shfl_up(s, off, 64);
        if (lane >= off) s += x;
      }
      if (lane < 16) wsum[lane] = s;
    }
    __syncthreads();
    int base = s_base;
    int woff = (w > 0) ? wsum[w - 1] : 0;
    int excl = base + woff + (val - v);
    if (i < N) { offs[i] = excl; cursor[i] = excl; }
    int total = wsum[15];
    __syncthreads();
    if (t == 0) s_base = base + total;
    __syncthreads();
  }
  if (t == 0) offs[N] = s_base;
}

__global__ void k_scatter(const int* __restrict__ ei, int E, int N,
                          int* __restrict__ cursor, int* __restrict__ csr_src) {
  int e = blockIdx.x * blockDim.x + threadIdx.x;
  int T = E + N;
  if (e == 0) csr_src[T] = 0;  // sentinel for prefetch
  if (e >= T) return;
  int s, d;
  if (e < E) { s = ei[e]; d = ei[E + e]; } else { s = d = e - E; }
  int pos = atomicAdd(&cursor[d], 1);
  csr_src[pos] = s;
}

// ---------------- fp16 MFMA GEMM: C[M,Ntot] = A[M,K] @ BT[Ntot,K]^T ----------------
// 128x128 tile, BK=64, 256 threads (4 waves, 2x2 of 64x64), 16x16x32 MFMA.
// LDS XOR-swizzle: slot' = slot ^ (row&7); staged linearly via pre-swizzled global src.
__global__ __launch_bounds__(256) void k_hgemm(const _Float16* __restrict__ A,
                                               const _Float16* __restrict__ BT,
                                               _Float16* __restrict__ C,
                                               int M, int Ntot, int K) {
  __shared__ _Float16 As[128 * 64];
  __shared__ _Float16 Bs[128 * 64];
  const int t = threadIdx.x;
  const int lane = t & 63, w = t >> 6;
  const int wr = w >> 1, wc = w & 1;
  const int bm0 = blockIdx.x * 128, bn0 = blockIdx.y * 128;
  f32x4 acc[4][4] = {};
  const int nkt = K >> 6;
  for (int kt = 0; kt < nkt; ++kt) {
    __syncthreads();  // previous iteration's readers done
    #pragma unroll
    for (int i = 0; i < 4; ++i) {
      int q = (i * 4 + w) * 64 + lane;        // 0..1023 slot id (16B slots)
      int row = q >> 3, sl = q & 7;
      int ssrc = sl ^ (row & 7);
      int ga = bm0 + row; if (ga >= M) ga = M - 1;
      async_copy16(&A[(size_t)ga * K + kt * 64 + ssrc * 8], &As[q * 8]);
      async_copy16(&BT[(size_t)(bn0 + row) * K + kt * 64 + ssrc * 8], &Bs[q * 8]);
    }
    __syncthreads();  // drains vmcnt before barrier -> staging visible
    #pragma unroll
    for (int ks = 0; ks < 2; ++ks) {
      f16x8 a[4], b[4];
      const int sl = ks * 4 + (lane >> 4);
      #pragma unroll
      for (int mi = 0; mi < 4; ++mi) {
        int row = wr * 64 + mi * 16 + (lane & 15);
        a[mi] = *(const f16x8*)&As[(row * 8 + (sl ^ (row & 7))) * 8];
      }
      #pragma unroll
      for (int ni = 0; ni < 4; ++ni) {
        int row = wc * 64 + ni * 16 + (lane & 15);
        b[ni] = *(const f16x8*)&Bs[(row * 8 + (sl ^ (row & 7))) * 8];
      }
      #pragma unroll
      for (int mi = 0; mi < 4; ++mi)
        #pragma unroll
        for (int ni = 0; ni < 4; ++ni)
          acc[mi][ni] = __builtin_amdgcn_mfma_f32_16x16x32_f16(a[mi], b[ni], acc[mi][ni], 0, 0, 0);
    }
  }
  const int r0 = (lane >> 4) * 4;
  const int cc = lane & 15;
  #pragma unroll
  for (int mi = 0; mi < 4; ++mi) {
    #pragma unroll
    for (int r = 0; r < 4; ++r) {
      int row = bm0 + wr * 64 + mi * 16 + r0 + r;
      if (row >= M) continue;
      #pragma unroll
      for (int ni = 0; ni < 4; ++ni) {
        int col = bn0 + wc * 64 + ni * 16 + cc;
        C[(size_t)row * Ntot + col] = (_Float16)acc[mi][ni][r];
      }
    }
  }
}

// ---------------- fused GATv2 edge phase, H=4, F=64 (Hm=256), fp16 in ----------------
// 128 threads/node (2 waves); lane owns channels 2t,2t+1 (uint load); head = 32-lane group.
__global__ __launch_bounds__(128) void k_gat4(const _Float16* __restrict__ xlr,  // [N][512]: xl|xr
                                              const float* __restrict__ att, const float* __restrict__ bias,
                                              const float* __restrict__ g, const float* __restrict__ bb,
                                              const float* __restrict__ rm, const float* __restrict__ rv,
                                              const int* __restrict__ offs, const int* __restrict__ csr,
                                              _Float16* __restrict__ hout) {  // [N][256]
  const int n = blockIdx.x;
  const int t = threadIdx.x;            // 0..127
  const int c0 = 2 * t, c1 = c0 + 1;
  const unsigned int* xu = (const unsigned int*)xlr;   // row stride 256 uints
  const float2 xr = unpack2(xu[(size_t)n * 256 + 128 + t]);
  const float a0 = att[c0], a1 = att[c1];
  const int j0 = offs[n], j1 = offs[n + 1];

  int s = csr[j0];
  unsigned int vu = xu[(size_t)s * 256 + t];
  int sn = csr[j0 + 1];
  unsigned int vun = xu[(size_t)sn * 256 + t];

  float m, l, acc0, acc1;
  {
    float2 v = unpack2(vu);
    float s0 = v.x + xr.x; s0 = s0 > 0.f ? s0 : NEG_SLOPE * s0;
    float s1 = v.y + xr.y; s1 = s1 > 0.f ? s1 : NEG_SLOPE * s1;
    float e = s0 * a0 + s1 * a1;
    #pragma unroll
    for (int off = 1; off < 32; off <<= 1) e += __shfl_xor(e, off, 64);
    m = e; l = 1.f; acc0 = v.x; acc1 = v.y;
  }
  for (int j = j0 + 1; j < j1; ++j) {
    vu = vun;
    int s2 = csr[j + 1];                 // padded: csr[T] valid
    vun = xu[(size_t)s2 * 256 + t];      // prefetch next edge row
    float2 v = unpack2(vu);
    float s0 = v.x + xr.x; s0 = s0 > 0.f ? s0 : NEG_SLOPE * s0;
    float s1 = v.y + xr.y; s1 = s1 > 0.f ? s1 : NEG_SLOPE * s1;
    float e = s0 * a0 + s1 * a1;
    #pragma unroll
    for (int off = 1; off < 32; off <<= 1) e += __shfl_xor(e, off, 64);
    float mn = fmaxf(m, e);
    float c = __expf(m - mn), pe = __expf(e - mn);
    l = l * c + pe;
    acc0 = acc0 * c + pe * v.x;
    acc1 = acc1 * c + pe * v.y;
    m = mn;
  }
  float o0 = acc0 / l + bias[c0];
  float o1 = acc1 / l + bias[c1];
  o0 = (o0 - rm[c0]) * rsqrtf(rv[c0] + BN_EPS) * g[c0] + bb[c0];
  o1 = (o1 - rm[c1]) * rsqrtf(rv[c1] + BN_EPS) * g[c1] + bb[c1];
  o0 = o0 > 0.f ? o0 : (__expf(o0) - 1.f);
  o1 = o1 > 0.f ? o1 : (__expf(o1) - 1.f);
  ((unsigned int*)hout)[(size_t)n * 128 + t] = pack2(o0, o1);
}

// ---------------- fused GATv2 edge phase, H=1, F=128 (layer 3), fp16 in, fp32 out ----
__global__ __launch_bounds__(64) void k_gat1(const _Float16* __restrict__ xlr,  // [N][256]: xl|xr
                                             const float* __restrict__ att, const float* __restrict__ bias,
                                             const int* __restrict__ offs, const int* __restrict__ csr,
                                             float* __restrict__ out) {  // [N][128] fp32
  const int n = blockIdx.x;
  const int t = threadIdx.x;            // 0..63
  const int c0 = 2 * t, c1 = c0 + 1;
  const unsigned int* xu = (const unsigned int*)xlr;   // row stride 128 uints
  const float2 xr = unpack2(xu[(size_t)n * 128 + 64 + t]);
  const float a0 = att[c0], a1 = att[c1];
  const int j0 = offs[n], j1 = offs[n + 1];

  int s = csr[j0];
  unsigned int vu = xu[(size_t)s * 128 + t];
  int sn = csr[j0 + 1];
  unsigned int vun = xu[(size_t)sn * 128 + t];

  float m, l, acc0, acc1;
  {
    float2 v = unpack2(vu);
    float s0 = v.x + xr.x; s0 = s0 > 0.f ? s0 : NEG_SLOPE * s0;
    float s1 = v.y + xr.y; s1 = s1 > 0.f ? s1 : NEG_SLOPE * s1;
    float e = s0 * a0 + s1 * a1;
    #pragma unroll
    for (int off = 1; off < 64; off <<= 1) e += __shfl_xor(e, off, 64);
    m = e; l = 1.f; acc0 = v.x; acc1 = v.y;
  }
  for (int j = j0 + 1; j < j1; ++j) {
    vu = vun;
    int s2 = csr[j + 1];
    vun = xu[(size_t)s2 * 128 + t];
    float2 v = unpack2(vu);
    float s0 = v.x + xr.x; s0 = s0 > 0.f ? s0 : NEG_SLOPE * s0;
    float s1 = v.y + xr.y; s1 = s1 > 0.f ? s1 : NEG_SLOPE * s1;
    float e = s0 * a0 + s1 * a1;
    #pragma unroll
    for (int off = 1; off < 64; off <<= 1) e += __shfl_xor(e, off, 64);
    float mn = fmaxf(m, e);
    float c = __expf(m - mn), pe = __expf(e - mn);
    l = l * c + pe;
    acc0 = acc0 * c + pe * v.x;
    acc1 = acc1 * c + pe * v.y;
    m = mn;
  }
  float2 o = make_float2(acc0 / l + bias[c0], acc1 / l + bias[c1]);
  reinterpret_cast<float2*>(out)[(size_t)n * 64 + t] = o;
}

extern "C" void kernel_launch(void* const* d_in, const int* in_sizes, int n_in,
                              void* d_out, int out_size, void* d_ws, size_t ws_size,
                              hipStream_t stream) {
  const float* x    = (const float*)d_in[0];
  const int*   ei   = (const int*)d_in[1];
  const float* Wl1  = (const float*)d_in[2];
  const float* Wr1  = (const float*)d_in[3];
  const float* att1 = (const float*)d_in[4];
  const float* b1   = (const float*)d_in[5];
  const float* bn1g = (const float*)d_in[6];
  const float* bn1b = (const float*)d_in[7];
  const float* bn1m = (const float*)d_in[8];
  const float* bn1v = (const float*)d_in[9];
  const float* Wl2  = (const float*)d_in[10];
  const float* Wr2  = (const float*)d_in[11];
  const float* att2 = (const float*)d_in[12];
  const float* b2   = (const float*)d_in[13];
  const float* bn2g = (const float*)d_in[14];
  const float* bn2b = (const float*)d_in[15];
  const float* bn2m = (const float*)d_in[16];
  const float* bn2v = (const float*)d_in[17];
  const float* Wl3  = (const float*)d_in[18];
  const float* Wr3  = (const float*)d_in[19];
  const float* att3 = (const float*)d_in[20];
  const float* b3   = (const float*)d_in[21];

  const int Hm   = in_sizes[5];          // 256
  const int Cout = in_sizes[21];         // 128
  const int Cin  = in_sizes[2] / Hm;     // 128
  const int N    = in_sizes[0] / Cin;    // 50000
  const int E    = in_sizes[1] / 2;      // 800000
  const int T    = E + N;

  // workspace layout (fp16 counts are even -> all int sections stay 4B-aligned)
  _Float16* x16 = (_Float16*)d_ws;                 // N*Cin
  _Float16* h   = x16 + (size_t)N * Cin;           // N*Hm
  _Float16* xlr = h + (size_t)N * Hm;              // N*2*Hm
  _Float16* WT1 = xlr + (size_t)N * 2 * Hm;        // (2*Hm)*Cin
  _Float16* WT2 = WT1 + (size_t)2 * Hm * Cin;      // (2*Hm)*Hm
  _Float16* WT3 = WT2 + (size_t)2 * Hm * Hm;       // (2*Cout)*Hm
  int* deg    = (int*)(WT3 + (size_t)2 * Cout * Hm);
  int* offs   = deg + N;
  int* cursor = offs + N + 1;
  int* csr    = cursor + N;                        // T+1 entries (sentinel)

  // --- CSR build by dst ---
  k_zero_i32<<<(N + 255) / 256, 256, 0, stream>>>(deg, N);
  k_count<<<(T + 255) / 256, 256, 0, stream>>>(ei, E, N, deg);
  k_scan<<<1, 1024, 0, stream>>>(deg, N, offs, cursor);
  k_scatter<<<(T + 255) / 256, 256, 0, stream>>>(ei, E, N, cursor, csr);

  // --- convert inputs to fp16 ---
  int n2 = N * Cin / 2;
  k_f2h<<<(n2 + 255) / 256, 256, 0, stream>>>(x, (unsigned int*)x16, n2);
  k_prep_w<<<(2 * Hm * Cin + 255) / 256, 256, 0, stream>>>(Wl1, Wr1, Cin, Hm, WT1);
  k_prep_w<<<(2 * Hm * Hm + 255) / 256, 256, 0, stream>>>(Wl2, Wr2, Hm, Hm, WT2);
  k_prep_w<<<(2 * Cout * Hm + 255) / 256, 256, 0, stream>>>(Wl3, Wr3, Hm, Cout, WT3);

  const int mb = (N + 127) / 128;

  // --- layer 1 ---
  k_hgemm<<<dim3(mb, 2 * Hm / 128), 256, 0, stream>>>(x16, WT1, xlr, N, 2 * Hm, Cin);
  k_gat4<<<N, 128, 0, stream>>>(xlr, att1, b1, bn1g, bn1b, bn1m, bn1v, offs, csr, h);

  // --- layer 2 ---
  k_hgemm<<<dim3(mb, 2 * Hm / 128), 256, 0, stream>>>(h, WT2, xlr, N, 2 * Hm, Hm);
  k_gat4<<<N, 128, 0, stream>>>(xlr, att2, b2, bn2g, bn2b, bn2m, bn2v, offs, csr, h);

  // --- layer 3 ---
  k_hgemm<<<dim3(mb, 2 * Cout / 128), 256, 0, stream>>>(h, WT3, xlr, N, 2 * Cout, Hm);
  k_gat1<<<N, 64, 0, stream>>>(xlr, att3, b3, offs, csr, (float*)d_out);
}

// Round 3
// 451.895 us; speedup vs baseline: 2.6397x; 1.2916x over previous
//
#include <hip/hip_runtime.h>
#include <math.h>

#define NEG_SLOPE 0.2f
#define BN_EPS 1e-5f

typedef _Float16 f16x8 __attribute__((ext_vector_type(8)));
typedef float f32x4 __attribute__((ext_vector_type(4)));

__device__ __forceinline__ void async_copy16(const void* g, void* l) {
  __builtin_amdgcn_global_load_lds(
      (const __attribute__((address_space(1))) void*)g,
      (__attribute__((address_space(3))) void*)l, 16, 0, 0);
}

__device__ __forceinline__ float2 unpack2(unsigned int u) {
  union { unsigned int u; _Float16 h[2]; } c; c.u = u;
  return make_float2((float)c.h[0], (float)c.h[1]);
}
__device__ __forceinline__ unsigned int pack2(float a, float b) {
  union { unsigned int u; _Float16 h[2]; } c;
  c.h[0] = (_Float16)a; c.h[1] = (_Float16)b; return c.u;
}
__device__ __forceinline__ float4 unpack4(uint2 u) {
  union { uint2 u2; _Float16 h[4]; } c; c.u2 = u;
  return make_float4((float)c.h[0], (float)c.h[1], (float)c.h[2], (float)c.h[3]);
}
__device__ __forceinline__ uint2 pack4(float4 v) {
  union { uint2 u2; _Float16 h[4]; } c;
  c.h[0] = (_Float16)v.x; c.h[1] = (_Float16)v.y;
  c.h[2] = (_Float16)v.z; c.h[3] = (_Float16)v.w;
  return c.u2;
}

// ---------------- utility ----------------
__global__ void k_zero_i32(int* __restrict__ p, int n) {
  int i = blockIdx.x * blockDim.x + threadIdx.x;
  if (i < n) p[i] = 0;
}

__global__ void k_f2h(const float* __restrict__ in, unsigned int* __restrict__ out, int n2) {
  int i = blockIdx.x * blockDim.x + threadIdx.x;
  if (i < n2) {
    float2 v = reinterpret_cast<const float2*>(in)[i];
    out[i] = pack2(v.x, v.y);
  }
}

// WT[c][k] = (c<Ch ? Wl[k][c] : Wr[k][c-Ch]) as fp16; WT is [2*Ch][K]
__global__ void k_prep_w(const float* __restrict__ Wl, const float* __restrict__ Wr,
                         int K, int Ch, _Float16* __restrict__ WT) {
  int i = blockIdx.x * blockDim.x + threadIdx.x;
  int total = 2 * Ch * K;
  if (i >= total) return;
  int c = i / K, k = i % K;
  float v = (c < Ch) ? Wl[(size_t)k * Ch + c] : Wr[(size_t)k * Ch + (c - Ch)];
  WT[i] = (_Float16)v;
}

// ---------------- CSR build (group edges by dst) ----------------
__global__ void k_count(const int* __restrict__ ei, int E, int N, int* __restrict__ deg) {
  int e = blockIdx.x * blockDim.x + threadIdx.x;
  int T = E + N;
  if (e >= T) return;
  int d = (e < E) ? ei[E + e] : (e - E);
  atomicAdd(&deg[d], 1);
}

__global__ __launch_bounds__(1024) void k_scan(const int* __restrict__ deg, int N,
                                               int* __restrict__ offs, int* __restrict__ cursor) {
  __shared__ int wsum[16];
  __shared__ int s_base;
  int t = threadIdx.x;
  int lane = t & 63, w = t >> 6;
  if (t == 0) s_base = 0;
  __syncthreads();
  for (int start = 0; start < N; start += 1024) {
    int i = start + t;
    int v = (i < N) ? deg[i] : 0;
    int val = v;
    #pragma unroll
    for (int off = 1; off < 64; off <<= 1) {
      int x = __shfl_up(val, off, 64);
      if (lane >= off) val += x;
    }
    if (lane == 63) wsum[w] = val;
    __syncthreads();
    if (w == 0) {
      int s = (lane < 16) ? wsum[lane] : 0;
      #pragma unroll
      for (int off = 1; off < 16; off <<= 1) {
        int x = __shfl_up(s, off, 64);
        if (lane >= off) s += x;
      }
      if (lane < 16) wsum[lane] = s;
    }
    __syncthreads();
    int base = s_base;
    int woff = (w > 0) ? wsum[w - 1] : 0;
    int excl = base + woff + (val - v);
    if (i < N) { offs[i] = excl; cursor[i] = excl; }
    int total = wsum[15];
    __syncthreads();
    if (t == 0) s_base = base + total;
    __syncthreads();
  }
  if (t == 0) offs[N] = s_base;
}

__global__ void k_scatter(const int* __restrict__ ei, int E, int N,
                          int* __restrict__ cursor, int* __restrict__ csr_src) {
  int e = blockIdx.x * blockDim.x + threadIdx.x;
  int T = E + N;
  if (e < 4) csr_src[T + e] = 0;  // sentinels for prefetch
  if (e >= T) return;
  int s, d;
  if (e < E) { s = ei[e]; d = ei[E + e]; } else { s = d = e - E; }
  int pos = atomicAdd(&cursor[d], 1);
  csr_src[pos] = s;
}

// ---------------- fp16 MFMA GEMM: C[M,Ntot] = A[M,K] @ BT[Ntot,K]^T ----------------
__global__ __launch_bounds__(256) void k_hgemm(const _Float16* __restrict__ A,
                                               const _Float16* __restrict__ BT,
                                               _Float16* __restrict__ C,
                                               int M, int Ntot, int K) {
  __shared__ _Float16 As[128 * 64];
  __shared__ _Float16 Bs[128 * 64];
  const int t = threadIdx.x;
  const int lane = t & 63, w = t >> 6;
  const int wr = w >> 1, wc = w & 1;
  const int bm0 = blockIdx.x * 128, bn0 = blockIdx.y * 128;
  f32x4 acc[4][4] = {};
  const int nkt = K >> 6;
  for (int kt = 0; kt < nkt; ++kt) {
    __syncthreads();
    #pragma unroll
    for (int i = 0; i < 4; ++i) {
      int q = (i * 4 + w) * 64 + lane;
      int row = q >> 3, sl = q & 7;
      int ssrc = sl ^ (row & 7);
      int ga = bm0 + row; if (ga >= M) ga = M - 1;
      async_copy16(&A[(size_t)ga * K + kt * 64 + ssrc * 8], &As[q * 8]);
      async_copy16(&BT[(size_t)(bn0 + row) * K + kt * 64 + ssrc * 8], &Bs[q * 8]);
    }
    __syncthreads();
    #pragma unroll
    for (int ks = 0; ks < 2; ++ks) {
      f16x8 a[4], b[4];
      const int sl = ks * 4 + (lane >> 4);
      #pragma unroll
      for (int mi = 0; mi < 4; ++mi) {
        int row = wr * 64 + mi * 16 + (lane & 15);
        a[mi] = *(const f16x8*)&As[(row * 8 + (sl ^ (row & 7))) * 8];
      }
      #pragma unroll
      for (int ni = 0; ni < 4; ++ni) {
        int row = wc * 64 + ni * 16 + (lane & 15);
        b[ni] = *(const f16x8*)&Bs[(row * 8 + (sl ^ (row & 7))) * 8];
      }
      #pragma unroll
      for (int mi = 0; mi < 4; ++mi)
        #pragma unroll
        for (int ni = 0; ni < 4; ++ni)
          acc[mi][ni] = __builtin_amdgcn_mfma_f32_16x16x32_f16(a[mi], b[ni], acc[mi][ni], 0, 0, 0);
    }
  }
  const int r0 = (lane >> 4) * 4;
  const int cc = lane & 15;
  #pragma unroll
  for (int mi = 0; mi < 4; ++mi) {
    #pragma unroll
    for (int r = 0; r < 4; ++r) {
      int row = bm0 + wr * 64 + mi * 16 + r0 + r;
      if (row >= M) continue;
      #pragma unroll
      for (int ni = 0; ni < 4; ++ni) {
        int col = bn0 + wc * 64 + ni * 16 + cc;
        C[(size_t)row * Ntot + col] = (_Float16)acc[mi][ni][r];
      }
    }
  }
}

// ---------------- fused GATv2 edge phase, H=4, F=64 (Hm=256), fp16 in ----------------
// 1 wave per node (2 nodes / 128-thread block); lane owns channels 4l..4l+3.
// Head = 16-lane group; online softmax, 2-edge unroll, 1-pair prefetch.
__global__ __launch_bounds__(128) void k_gat4(const _Float16* __restrict__ xlr,  // [N][512]: xl|xr
                                              const float* __restrict__ att, const float* __restrict__ bias,
                                              const float* __restrict__ g, const float* __restrict__ bb,
                                              const float* __restrict__ rm, const float* __restrict__ rv,
                                              const int* __restrict__ offs, const int* __restrict__ csr,
                                              int N, _Float16* __restrict__ hout) {  // [N][256]
  const int n = blockIdx.x * 2 + (threadIdx.x >> 6);
  if (n >= N) return;
  const int l4 = (threadIdx.x & 63);
  const uint2* xu2 = (const uint2*)xlr;               // row stride 128 uint2
  const float4 xr4 = unpack4(xu2[(size_t)n * 128 + 64 + l4]);
  const float4 at4 = reinterpret_cast<const float4*>(att)[l4];
  const int j0 = offs[n], j1 = offs[n + 1];

  float m = -INFINITY, l = 0.f;
  float4 acc = make_float4(0.f, 0.f, 0.f, 0.f);

  int j = j0;
  int s1 = csr[j0], s2 = csr[j0 + 1];
  uint2 u1 = xu2[(size_t)s1 * 128 + l4];
  uint2 u2 = xu2[(size_t)s2 * 128 + l4];

  for (; j + 1 < j1; j += 2) {
    int s1n = csr[j + 2], s2n = csr[j + 3];          // csr padded with 4 sentinels
    uint2 u1n = xu2[(size_t)s1n * 128 + l4];
    uint2 u2n = xu2[(size_t)s2n * 128 + l4];

    float4 v1 = unpack4(u1), v2 = unpack4(u2);
    float t0, e1, e2;
    t0 = v1.x + xr4.x; t0 = t0 > 0.f ? t0 : NEG_SLOPE * t0; e1  = t0 * at4.x;
    t0 = v1.y + xr4.y; t0 = t0 > 0.f ? t0 : NEG_SLOPE * t0; e1 += t0 * at4.y;
    t0 = v1.z + xr4.z; t0 = t0 > 0.f ? t0 : NEG_SLOPE * t0; e1 += t0 * at4.z;
    t0 = v1.w + xr4.w; t0 = t0 > 0.f ? t0 : NEG_SLOPE * t0; e1 += t0 * at4.w;
    t0 = v2.x + xr4.x; t0 = t0 > 0.f ? t0 : NEG_SLOPE * t0; e2  = t0 * at4.x;
    t0 = v2.y + xr4.y; t0 = t0 > 0.f ? t0 : NEG_SLOPE * t0; e2 += t0 * at4.y;
    t0 = v2.z + xr4.z; t0 = t0 > 0.f ? t0 : NEG_SLOPE * t0; e2 += t0 * at4.z;
    t0 = v2.w + xr4.w; t0 = t0 > 0.f ? t0 : NEG_SLOPE * t0; e2 += t0 * at4.w;
    #pragma unroll
    for (int off = 1; off < 16; off <<= 1) {
      e1 += __shfl_xor(e1, off, 64);
      e2 += __shfl_xor(e2, off, 64);
    }
    float mn = fmaxf(m, fmaxf(e1, e2));
    float c  = __expf(m - mn);
    float p1 = __expf(e1 - mn);
    float p2 = __expf(e2 - mn);
    l = l * c + p1 + p2;
    acc.x = acc.x * c + p1 * v1.x + p2 * v2.x;
    acc.y = acc.y * c + p1 * v1.y + p2 * v2.y;
    acc.z = acc.z * c + p1 * v1.z + p2 * v2.z;
    acc.w = acc.w * c + p1 * v1.w + p2 * v2.w;
    m = mn;
    u1 = u1n; u2 = u2n;
  }
  if (j < j1) {  // odd tail
    float4 v1 = unpack4(u1);
    float t0, e1;
    t0 = v1.x + xr4.x; t0 = t0 > 0.f ? t0 : NEG_SLOPE * t0; e1  = t0 * at4.x;
    t0 = v1.y + xr4.y; t0 = t0 > 0.f ? t0 : NEG_SLOPE * t0; e1 += t0 * at4.y;
    t0 = v1.z + xr4.z; t0 = t0 > 0.f ? t0 : NEG_SLOPE * t0; e1 += t0 * at4.z;
    t0 = v1.w + xr4.w; t0 = t0 > 0.f ? t0 : NEG_SLOPE * t0; e1 += t0 * at4.w;
    #pragma unroll
    for (int off = 1; off < 16; off <<= 1) e1 += __shfl_xor(e1, off, 64);
    float mn = fmaxf(m, e1);
    float c  = __expf(m - mn);
    float p1 = __expf(e1 - mn);
    l = l * c + p1;
    acc.x = acc.x * c + p1 * v1.x;
    acc.y = acc.y * c + p1 * v1.y;
    acc.z = acc.z * c + p1 * v1.z;
    acc.w = acc.w * c + p1 * v1.w;
  }
  const float4 b4  = reinterpret_cast<const float4*>(bias)[l4];
  const float4 rm4 = reinterpret_cast<const float4*>(rm)[l4];
  const float4 rv4 = reinterpret_cast<const float4*>(rv)[l4];
  const float4 g4  = reinterpret_cast<const float4*>(g)[l4];
  const float4 bb4 = reinterpret_cast<const float4*>(bb)[l4];
  float inv = 1.f / l;
  float4 o;
  o.x = (acc.x * inv + b4.x - rm4.x) * rsqrtf(rv4.x + BN_EPS) * g4.x + bb4.x;
  o.y = (acc.y * inv + b4.y - rm4.y) * rsqrtf(rv4.y + BN_EPS) * g4.y + bb4.y;
  o.z = (acc.z * inv + b4.z - rm4.z) * rsqrtf(rv4.z + BN_EPS) * g4.z + bb4.z;
  o.w = (acc.w * inv + b4.w - rm4.w) * rsqrtf(rv4.w + BN_EPS) * g4.w + bb4.w;
  o.x = o.x > 0.f ? o.x : (__expf(o.x) - 1.f);
  o.y = o.y > 0.f ? o.y : (__expf(o.y) - 1.f);
  o.z = o.z > 0.f ? o.z : (__expf(o.z) - 1.f);
  o.w = o.w > 0.f ? o.w : (__expf(o.w) - 1.f);
  ((uint2*)hout)[(size_t)n * 64 + l4] = pack4(o);
}

// ---------------- fused GATv2 edge phase, H=1, F=128 (layer 3) ----------------
// 1 wave per node (2 nodes / block); lane owns channels 2l,2l+1; full 64-lane reduce.
__global__ __launch_bounds__(128) void k_gat1(const _Float16* __restrict__ xlr,  // [N][256]: xl|xr
                                              const float* __restrict__ att, const float* __restrict__ bias,
                                              const int* __restrict__ offs, const int* __restrict__ csr,
                                              int N, float* __restrict__ out) {  // [N][128] fp32
  const int n = blockIdx.x * 2 + (threadIdx.x >> 6);
  if (n >= N) return;
  const int l2 = (threadIdx.x & 63);
  const unsigned int* xu = (const unsigned int*)xlr;   // row stride 128 uints
  const float2 xr = unpack2(xu[(size_t)n * 128 + 64 + l2]);
  const float2 a2 = reinterpret_cast<const float2*>(att)[l2];
  const int j0 = offs[n], j1 = offs[n + 1];

  float m = -INFINITY, l = 0.f, acc0 = 0.f, acc1 = 0.f;

  int j = j0;
  int s1 = csr[j0], s2 = csr[j0 + 1];
  unsigned int u1 = xu[(size_t)s1 * 128 + l2];
  unsigned int u2 = xu[(size_t)s2 * 128 + l2];

  for (; j + 1 < j1; j += 2) {
    int s1n = csr[j + 2], s2n = csr[j + 3];
    unsigned int u1n = xu[(size_t)s1n * 128 + l2];
    unsigned int u2n = xu[(size_t)s2n * 128 + l2];

    float2 v1 = unpack2(u1), v2 = unpack2(u2);
    float t0, e1, e2;
    t0 = v1.x + xr.x; t0 = t0 > 0.f ? t0 : NEG_SLOPE * t0; e1  = t0 * a2.x;
    t0 = v1.y + xr.y; t0 = t0 > 0.f ? t0 : NEG_SLOPE * t0; e1 += t0 * a2.y;
    t0 = v2.x + xr.x; t0 = t0 > 0.f ? t0 : NEG_SLOPE * t0; e2  = t0 * a2.x;
    t0 = v2.y + xr.y; t0 = t0 > 0.f ? t0 : NEG_SLOPE * t0; e2 += t0 * a2.y;
    #pragma unroll
    for (int off = 1; off < 64; off <<= 1) {
      e1 += __shfl_xor(e1, off, 64);
      e2 += __shfl_xor(e2, off, 64);
    }
    float mn = fmaxf(m, fmaxf(e1, e2));
    float c  = __expf(m - mn);
    float p1 = __expf(e1 - mn);
    float p2 = __expf(e2 - mn);
    l = l * c + p1 + p2;
    acc0 = acc0 * c + p1 * v1.x + p2 * v2.x;
    acc1 = acc1 * c + p1 * v1.y + p2 * v2.y;
    m = mn;
    u1 = u1n; u2 = u2n;
  }
  if (j < j1) {
    float2 v1 = unpack2(u1);
    float t0, e1;
    t0 = v1.x + xr.x; t0 = t0 > 0.f ? t0 : NEG_SLOPE * t0; e1  = t0 * a2.x;
    t0 = v1.y + xr.y; t0 = t0 > 0.f ? t0 : NEG_SLOPE * t0; e1 += t0 * a2.y;
    #pragma unroll
    for (int off = 1; off < 64; off <<= 1) e1 += __shfl_xor(e1, off, 64);
    float mn = fmaxf(m, e1);
    float c  = __expf(m - mn);
    float p1 = __expf(e1 - mn);
    l = l * c + p1;
    acc0 = acc0 * c + p1 * v1.x;
    acc1 = acc1 * c + p1 * v1.y;
  }
  float inv = 1.f / l;
  const float2 b2 = reinterpret_cast<const float2*>(bias)[l2];
  float2 o = make_float2(acc0 * inv + b2.x, acc1 * inv + b2.y);
  reinterpret_cast<float2*>(out)[(size_t)n * 64 + l2] = o;
}

extern "C" void kernel_launch(void* const* d_in, const int* in_sizes, int n_in,
                              void* d_out, int out_size, void* d_ws, size_t ws_size,
                              hipStream_t stream) {
  const float* x    = (const float*)d_in[0];
  const int*   ei   = (const int*)d_in[1];
  const float* Wl1  = (const float*)d_in[2];
  const float* Wr1  = (const float*)d_in[3];
  const float* att1 = (const float*)d_in[4];
  const float* b1   = (const float*)d_in[5];
  const float* bn1g = (const float*)d_in[6];
  const float* bn1b = (const float*)d_in[7];
  const float* bn1m = (const float*)d_in[8];
  const float* bn1v = (const float*)d_in[9];
  const float* Wl2  = (const float*)d_in[10];
  const float* Wr2  = (const float*)d_in[11];
  const float* att2 = (const float*)d_in[12];
  const float* b2   = (const float*)d_in[13];
  const float* bn2g = (const float*)d_in[14];
  const float* bn2b = (const float*)d_in[15];
  const float* bn2m = (const float*)d_in[16];
  const float* bn2v = (const float*)d_in[17];
  const float* Wl3  = (const float*)d_in[18];
  const float* Wr3  = (const float*)d_in[19];
  const float* att3 = (const float*)d_in[20];
  const float* b3   = (const float*)d_in[21];

  const int Hm   = in_sizes[5];          // 256
  const int Cout = in_sizes[21];         // 128
  const int Cin  = in_sizes[2] / Hm;     // 128
  const int N    = in_sizes[0] / Cin;    // 50000
  const int E    = in_sizes[1] / 2;      // 800000
  const int T    = E + N;

  _Float16* x16 = (_Float16*)d_ws;                 // N*Cin
  _Float16* h   = x16 + (size_t)N * Cin;           // N*Hm
  _Float16* xlr = h + (size_t)N * Hm;              // N*2*Hm
  _Float16* WT1 = xlr + (size_t)N * 2 * Hm;        // (2*Hm)*Cin
  _Float16* WT2 = WT1 + (size_t)2 * Hm * Cin;      // (2*Hm)*Hm
  _Float16* WT3 = WT2 + (size_t)2 * Hm * Hm;       // (2*Cout)*Hm
  int* deg    = (int*)(WT3 + (size_t)2 * Cout * Hm);
  int* offs   = deg + N;
  int* cursor = offs + N + 1;
  int* csr    = cursor + N;                        // T+4 entries (sentinels)

  // --- CSR build by dst ---
  k_zero_i32<<<(N + 255) / 256, 256, 0, stream>>>(deg, N);
  k_count<<<(T + 255) / 256, 256, 0, stream>>>(ei, E, N, deg);
  k_scan<<<1, 1024, 0, stream>>>(deg, N, offs, cursor);
  k_scatter<<<(T + 255) / 256, 256, 0, stream>>>(ei, E, N, cursor, csr);

  // --- convert inputs to fp16 ---
  int n2 = N * Cin / 2;
  k_f2h<<<(n2 + 255) / 256, 256, 0, stream>>>(x, (unsigned int*)x16, n2);
  k_prep_w<<<(2 * Hm * Cin + 255) / 256, 256, 0, stream>>>(Wl1, Wr1, Cin, Hm, WT1);
  k_prep_w<<<(2 * Hm * Hm + 255) / 256, 256, 0, stream>>>(Wl2, Wr2, Hm, Hm, WT2);
  k_prep_w<<<(2 * Cout * Hm + 255) / 256, 256, 0, stream>>>(Wl3, Wr3, Hm, Cout, WT3);

  const int mb = (N + 127) / 128;
  const int gb = (N + 1) / 2;

  // --- layer 1 ---
  k_hgemm<<<dim3(mb, 2 * Hm / 128), 256, 0, stream>>>(x16, WT1, xlr, N, 2 * Hm, Cin);
  k_gat4<<<gb, 128, 0, stream>>>(xlr, att1, b1, bn1g, bn1b, bn1m, bn1v, offs, csr, N, h);

  // --- layer 2 ---
  k_hgemm<<<dim3(mb, 2 * Hm / 128), 256, 0, stream>>>(h, WT2, xlr, N, 2 * Hm, Hm);
  k_gat4<<<gb, 128, 0, stream>>>(xlr, att2, b2, bn2g, bn2b, bn2m, bn2v, offs, csr, N, h);

  // --- layer 3 ---
  k_hgemm<<<dim3(mb, 2 * Cout / 128), 256, 0, stream>>>(h, WT3, xlr, N, 2 * Cout, Hm);
  k_gat1<<<gb, 128, 0, stream>>>(xlr, att3, b3, offs, csr, N, (float*)d_out);
}

// Round 4
// 405.201 us; speedup vs baseline: 2.9439x; 1.1152x over previous
//
#include <hip/hip_runtime.h>
#include <math.h>

#define NEG_SLOPE 0.2f
#define BN_EPS 1e-5f

typedef _Float16 f16x8 __attribute__((ext_vector_type(8)));
typedef float f32x4 __attribute__((ext_vector_type(4)));
typedef _Float16 h2 __attribute__((ext_vector_type(2)));

union U2 { uint2 u; h2 h[2]; };
union U1 { unsigned u; h2 h; };

__device__ __forceinline__ void async_copy16(const void* g, void* l) {
  __builtin_amdgcn_global_load_lds(
      (const __attribute__((address_space(1))) void*)g,
      (__attribute__((address_space(3))) void*)l, 16, 0, 0);
}

__device__ __forceinline__ h2 shfl_xor_h2(h2 v, int off) {
  U1 c; c.h = v;
  c.u = __shfl_xor(c.u, off, 64);
  return c.h;
}

__device__ __forceinline__ unsigned int pack2f(float a, float b) {
  union { unsigned int u; _Float16 h[2]; } c;
  c.h[0] = (_Float16)a; c.h[1] = (_Float16)b; return c.u;
}
__device__ __forceinline__ uint2 pack4f(float4 v) {
  union { uint2 u2; _Float16 h[4]; } c;
  c.h[0] = (_Float16)v.x; c.h[1] = (_Float16)v.y;
  c.h[2] = (_Float16)v.z; c.h[3] = (_Float16)v.w;
  return c.u2;
}

// ---------------- utility ----------------
__global__ void k_zero_i32(int* __restrict__ p, int n) {
  int i = blockIdx.x * blockDim.x + threadIdx.x;
  if (i < n) p[i] = 0;
}

__global__ void k_f2h(const float* __restrict__ in, unsigned int* __restrict__ out, int n2) {
  int i = blockIdx.x * blockDim.x + threadIdx.x;
  if (i < n2) {
    float2 v = reinterpret_cast<const float2*>(in)[i];
    out[i] = pack2f(v.x, v.y);
  }
}

// WT[c][k] = (c<Ch ? Wl[k][c] : Wr[k][c-Ch]) as fp16; WT is [2*Ch][K]
__global__ void k_prep_w(const float* __restrict__ Wl, const float* __restrict__ Wr,
                         int K, int Ch, _Float16* __restrict__ WT) {
  int i = blockIdx.x * blockDim.x + threadIdx.x;
  int total = 2 * Ch * K;
  if (i >= total) return;
  int c = i / K, k = i % K;
  float v = (c < Ch) ? Wl[(size_t)k * Ch + c] : Wr[(size_t)k * Ch + (c - Ch)];
  WT[i] = (_Float16)v;
}

// ---------------- CSR build (group edges by dst) ----------------
__global__ void k_count(const int* __restrict__ ei, int E, int N, int* __restrict__ deg) {
  int e = blockIdx.x * blockDim.x + threadIdx.x;
  int T = E + N;
  if (e >= T) return;
  int d = (e < E) ? ei[E + e] : (e - E);
  atomicAdd(&deg[d], 1);
}

// hierarchical scan: block sums -> scan sums -> per-block offsets
__global__ __launch_bounds__(256) void k_bsum(const int* __restrict__ deg, int N,
                                              int* __restrict__ bsum) {
  int t = threadIdx.x;
  int i = blockIdx.x * 256 + t;
  int v = (i < N) ? deg[i] : 0;
  #pragma unroll
  for (int off = 32; off > 0; off >>= 1) v += __shfl_xor(v, off, 64);
  __shared__ int ws[4];
  if ((t & 63) == 0) ws[t >> 6] = v;
  __syncthreads();
  if (t == 0) bsum[blockIdx.x] = ws[0] + ws[1] + ws[2] + ws[3];
}

__global__ __launch_bounds__(1024) void k_bscan(int* __restrict__ bsum, int nb, int N,
                                                int* __restrict__ offs) {
  int t = threadIdx.x;
  int lane = t & 63, w = t >> 6;
  int v = (t < nb) ? bsum[t] : 0;
  int val = v;
  #pragma unroll
  for (int off = 1; off < 64; off <<= 1) {
    int x = __shfl_up(val, off, 64);
    if (lane >= off) val += x;
  }
  __shared__ int ws[16];
  if (lane == 63) ws[w] = val;
  __syncthreads();
  if (w == 0) {
    int s = (lane < 16) ? ws[lane] : 0;
    #pragma unroll
    for (int off = 1; off < 16; off <<= 1) {
      int x = __shfl_up(s, off, 64);
      if (lane >= off) s += x;
    }
    if (lane < 16) ws[lane] = s;
  }
  __syncthreads();
  int excl = (w > 0 ? ws[w - 1] : 0) + val - v;
  if (t < nb) bsum[t] = excl;
  if (t == nb - 1) offs[N] = excl + v;
}

__global__ __launch_bounds__(256) void k_boffs(const int* __restrict__ deg, int N,
                                               const int* __restrict__ bpre,
                                               int* __restrict__ offs, int* __restrict__ cursor) {
  int t = threadIdx.x;
  int i = blockIdx.x * 256 + t;
  int lane = t & 63, w = t >> 6;
  int v = (i < N) ? deg[i] : 0;
  int val = v;
  #pragma unroll
  for (int off = 1; off < 64; off <<= 1) {
    int x = __shfl_up(val, off, 64);
    if (lane >= off) val += x;
  }
  __shared__ int ws[4];
  if (lane == 63) ws[w] = val;
  __syncthreads();
  int wo = 0;
  #pragma unroll
  for (int k = 0; k < 4; ++k) if (k < w) wo += ws[k];
  int excl = bpre[blockIdx.x] + wo + val - v;
  if (i < N) { offs[i] = excl; cursor[i] = excl; }
}

__global__ void k_scatter(const int* __restrict__ ei, int E, int N,
                          int* __restrict__ cursor, int* __restrict__ csr_src) {
  int e = blockIdx.x * blockDim.x + threadIdx.x;
  int T = E + N;
  if (e < 4) csr_src[T + e] = 0;  // sentinels for prefetch
  if (e >= T) return;
  int s, d;
  if (e < E) { s = ei[e]; d = ei[E + e]; } else { s = d = e - E; }
  int pos = atomicAdd(&cursor[d], 1);
  csr_src[pos] = s;
}

// ---------------- fp16 MFMA GEMM: C[M,Ntot] = A[M,K] @ BT[Ntot,K]^T ----------------
// 128x128 tile, BK=64, 256 threads; double-buffered LDS with counted vmcnt.
__global__ __launch_bounds__(256) void k_hgemm(const _Float16* __restrict__ A,
                                               const _Float16* __restrict__ BT,
                                               _Float16* __restrict__ C,
                                               int M, int Ntot, int K) {
  __shared__ _Float16 As[2][128 * 64];
  __shared__ _Float16 Bs[2][128 * 64];
  const int t = threadIdx.x;
  const int lane = t & 63, w = t >> 6;
  const int wr = w >> 1, wc = w & 1;
  const int bm0 = blockIdx.x * 128, bn0 = blockIdx.y * 128;
  f32x4 acc[4][4] = {};
  const int nkt = K >> 6;

  auto stage = [&](int b, int kt) {
    #pragma unroll
    for (int i = 0; i < 4; ++i) {
      int q = (i * 4 + w) * 64 + lane;
      int row = q >> 3, sl = q & 7;
      int ssrc = sl ^ (row & 7);
      int ga = bm0 + row; if (ga >= M) ga = M - 1;
      async_copy16(&A[(size_t)ga * K + kt * 64 + ssrc * 8], &As[b][q * 8]);
      async_copy16(&BT[(size_t)(bn0 + row) * K + kt * 64 + ssrc * 8], &Bs[b][q * 8]);
    }
  };

  stage(0, 0);
  for (int kt = 0; kt < nkt; ++kt) {
    int cur = kt & 1;
    if (kt + 1 < nkt) {
      stage(cur ^ 1, kt + 1);
      asm volatile("s_waitcnt vmcnt(8)" ::: "memory");   // wait current stage only
    } else {
      asm volatile("s_waitcnt vmcnt(0)" ::: "memory");
    }
    __builtin_amdgcn_s_barrier();
    #pragma unroll
    for (int ks = 0; ks < 2; ++ks) {
      f16x8 a[4], b[4];
      const int sl = ks * 4 + (lane >> 4);
      #pragma unroll
      for (int mi = 0; mi < 4; ++mi) {
        int row = wr * 64 + mi * 16 + (lane & 15);
        a[mi] = *(const f16x8*)&As[cur][(row * 8 + (sl ^ (row & 7))) * 8];
      }
      #pragma unroll
      for (int ni = 0; ni < 4; ++ni) {
        int row = wc * 64 + ni * 16 + (lane & 15);
        b[ni] = *(const f16x8*)&Bs[cur][(row * 8 + (sl ^ (row & 7))) * 8];
      }
      #pragma unroll
      for (int mi = 0; mi < 4; ++mi)
        #pragma unroll
        for (int ni = 0; ni < 4; ++ni)
          acc[mi][ni] = __builtin_amdgcn_mfma_f32_16x16x32_f16(a[mi], b[ni], acc[mi][ni], 0, 0, 0);
    }
    __builtin_amdgcn_s_barrier();   // readers done before next overwrite
  }
  const int r0 = (lane >> 4) * 4;
  const int cc = lane & 15;
  #pragma unroll
  for (int mi = 0; mi < 4; ++mi) {
    #pragma unroll
    for (int r = 0; r < 4; ++r) {
      int row = bm0 + wr * 64 + mi * 16 + r0 + r;
      if (row >= M) continue;
      #pragma unroll
      for (int ni = 0; ni < 4; ++ni) {
        int col = bn0 + wc * 64 + ni * 16 + cc;
        C[(size_t)row * Ntot + col] = (_Float16)acc[mi][ni][r];
      }
    }
  }
}

// ---------------- fused GATv2 edge phase, H=4, F=64 (Hm=256), packed fp16 ------------
// 1 wave per node (2/block); lane owns 4 ch (2 x h2); head = 16-lane group.
// Packed score math, combined 2-edge reduce, defer-max online softmax.
__global__ __launch_bounds__(128) void k_gat4(const _Float16* __restrict__ xlr,  // [N][512]: xl|xr
                                              const float* __restrict__ att, const float* __restrict__ bias,
                                              const float* __restrict__ g, const float* __restrict__ bb,
                                              const float* __restrict__ rm, const float* __restrict__ rv,
                                              const int* __restrict__ offs, const int* __restrict__ csr,
                                              int N, _Float16* __restrict__ hout) {  // [N][256]
  const int n = blockIdx.x * 2 + (threadIdx.x >> 6);
  if (n >= N) return;
  const int l4 = (threadIdx.x & 63);
  const uint2* xbase = (const uint2*)xlr + l4;       // row stride 128 uint2
  U2 xru; xru.u = xbase[(size_t)n * 128 + 64];
  const h2 xr0 = xru.h[0], xr1 = xru.h[1];
  const float4 at = reinterpret_cast<const float4*>(att)[l4];
  const h2 at0 = {(_Float16)at.x, (_Float16)at.y};
  const h2 at1 = {(_Float16)at.z, (_Float16)at.w};
  const h2 k02 = {(_Float16)0.2f, (_Float16)0.2f};
  const int j0 = offs[n], j1 = offs[n + 1];

  float m = -INFINITY, l = 0.f;
  float4 acc = make_float4(0.f, 0.f, 0.f, 0.f);

  int j = j0;
  int s1 = csr[j0], s2 = csr[j0 + 1];
  uint2 u1 = xbase[(size_t)s1 * 128];
  uint2 u2 = xbase[(size_t)s2 * 128];

  for (; j + 1 < j1; j += 2) {
    int s1n = csr[j + 2], s2n = csr[j + 3];          // csr padded with 4 sentinels
    uint2 u1n = xbase[(size_t)s1n * 128];
    uint2 u2n = xbase[(size_t)s2n * 128];

    U2 c1, c2; c1.u = u1; c2.u = u2;
    h2 sA = c1.h[0] + xr0, sB = c1.h[1] + xr1;
    sA = __builtin_elementwise_max(sA, sA * k02);    // leaky-relu
    sB = __builtin_elementwise_max(sB, sB * k02);
    h2 dp1 = sA * at0 + sB * at1;
    h2 sC = c2.h[0] + xr0, sD = c2.h[1] + xr1;
    sC = __builtin_elementwise_max(sC, sC * k02);
    sD = __builtin_elementwise_max(sD, sD * k02);
    h2 dp2 = sC * at0 + sD * at1;

    // q = {edge1 partial, edge2 partial}; one reduce handles both edges
    h2 q = __builtin_shufflevector(dp1, dp2, 0, 2) + __builtin_shufflevector(dp1, dp2, 1, 3);
    #pragma unroll
    for (int off = 1; off < 16; off <<= 1) q += shfl_xor_h2(q, off);
    float e1 = (float)q[0], e2 = (float)q[1];

    float emax = fmaxf(e1, e2);
    if (__any(emax > m + 8.f)) {                     // defer-max: rescale rarely
      float mn = fmaxf(m, emax);
      float c0 = __expf(m - mn);
      l *= c0; acc.x *= c0; acc.y *= c0; acc.z *= c0; acc.w *= c0;
      m = mn;
    }
    float p1 = __expf(e1 - m), p2 = __expf(e2 - m);
    l += p1 + p2;
    acc.x += p1 * (float)c1.h[0][0] + p2 * (float)c2.h[0][0];
    acc.y += p1 * (float)c1.h[0][1] + p2 * (float)c2.h[0][1];
    acc.z += p1 * (float)c1.h[1][0] + p2 * (float)c2.h[1][0];
    acc.w += p1 * (float)c1.h[1][1] + p2 * (float)c2.h[1][1];
    u1 = u1n; u2 = u2n;
  }
  if (j < j1) {  // odd tail
    U2 c1; c1.u = u1;
    h2 sA = c1.h[0] + xr0, sB = c1.h[1] + xr1;
    sA = __builtin_elementwise_max(sA, sA * k02);
    sB = __builtin_elementwise_max(sB, sB * k02);
    h2 q = sA * at0 + sB * at1;
    #pragma unroll
    for (int off = 1; off < 16; off <<= 1) q += shfl_xor_h2(q, off);
    float e1 = (float)q[0] + (float)q[1];
    if (__any(e1 > m + 8.f)) {
      float mn = fmaxf(m, e1);
      float c0 = __expf(m - mn);
      l *= c0; acc.x *= c0; acc.y *= c0; acc.z *= c0; acc.w *= c0;
      m = mn;
    }
    float p1 = __expf(e1 - m);
    l += p1;
    acc.x += p1 * (float)c1.h[0][0];
    acc.y += p1 * (float)c1.h[0][1];
    acc.z += p1 * (float)c1.h[1][0];
    acc.w += p1 * (float)c1.h[1][1];
  }
  const int c0i = 4 * l4;
  const float4 b4  = reinterpret_cast<const float4*>(bias)[l4];
  const float4 rm4 = reinterpret_cast<const float4*>(rm)[l4];
  const float4 rv4 = reinterpret_cast<const float4*>(rv)[l4];
  const float4 g4  = reinterpret_cast<const float4*>(g)[l4];
  const float4 bb4 = reinterpret_cast<const float4*>(bb)[l4];
  (void)c0i;
  float inv = 1.f / l;
  float4 o;
  o.x = (acc.x * inv + b4.x - rm4.x) * rsqrtf(rv4.x + BN_EPS) * g4.x + bb4.x;
  o.y = (acc.y * inv + b4.y - rm4.y) * rsqrtf(rv4.y + BN_EPS) * g4.y + bb4.y;
  o.z = (acc.z * inv + b4.z - rm4.z) * rsqrtf(rv4.z + BN_EPS) * g4.z + bb4.z;
  o.w = (acc.w * inv + b4.w - rm4.w) * rsqrtf(rv4.w + BN_EPS) * g4.w + bb4.w;
  o.x = o.x > 0.f ? o.x : (__expf(o.x) - 1.f);
  o.y = o.y > 0.f ? o.y : (__expf(o.y) - 1.f);
  o.z = o.z > 0.f ? o.z : (__expf(o.z) - 1.f);
  o.w = o.w > 0.f ? o.w : (__expf(o.w) - 1.f);
  ((uint2*)hout)[(size_t)n * 64 + l4] = pack4f(o);
}

// ---------------- fused GATv2 edge phase, H=1, F=128 (layer 3) -----------------------
__global__ __launch_bounds__(128) void k_gat1(const _Float16* __restrict__ xlr,  // [N][256]: xl|xr
                                              const float* __restrict__ att, const float* __restrict__ bias,
                                              const int* __restrict__ offs, const int* __restrict__ csr,
                                              int N, float* __restrict__ out) {  // [N][128] fp32
  const int n = blockIdx.x * 2 + (threadIdx.x >> 6);
  if (n >= N) return;
  const int l2 = (threadIdx.x & 63);
  const unsigned int* xbase = (const unsigned int*)xlr + l2;   // row stride 128 uints
  U1 xru; xru.u = xbase[(size_t)n * 128 + 64];
  const h2 xr0 = xru.h;
  const float2 a2 = reinterpret_cast<const float2*>(att)[l2];
  const h2 at0 = {(_Float16)a2.x, (_Float16)a2.y};
  const h2 k02 = {(_Float16)0.2f, (_Float16)0.2f};
  const int j0 = offs[n], j1 = offs[n + 1];

  float m = -INFINITY, l = 0.f, acc0 = 0.f, acc1 = 0.f;

  int j = j0;
  int s1 = csr[j0], s2 = csr[j0 + 1];
  unsigned int u1 = xbase[(size_t)s1 * 128];
  unsigned int u2 = xbase[(size_t)s2 * 128];

  for (; j + 1 < j1; j += 2) {
    int s1n = csr[j + 2], s2n = csr[j + 3];
    unsigned int u1n = xbase[(size_t)s1n * 128];
    unsigned int u2n = xbase[(size_t)s2n * 128];

    U1 c1, c2; c1.u = u1; c2.u = u2;
    h2 sA = c1.h + xr0;
    sA = __builtin_elementwise_max(sA, sA * k02);
    h2 dp1 = sA * at0;
    h2 sC = c2.h + xr0;
    sC = __builtin_elementwise_max(sC, sC * k02);
    h2 dp2 = sC * at0;

    h2 q = __builtin_shufflevector(dp1, dp2, 0, 2) + __builtin_shufflevector(dp1, dp2, 1, 3);
    #pragma unroll
    for (int off = 1; off < 64; off <<= 1) q += shfl_xor_h2(q, off);
    float e1 = (float)q[0], e2 = (float)q[1];

    float emax = fmaxf(e1, e2);
    if (__any(emax > m + 8.f)) {
      float mn = fmaxf(m, emax);
      float c0 = __expf(m - mn);
      l *= c0; acc0 *= c0; acc1 *= c0;
      m = mn;
    }
    float p1 = __expf(e1 - m), p2 = __expf(e2 - m);
    l += p1 + p2;
    acc0 += p1 * (float)c1.h[0] + p2 * (float)c2.h[0];
    acc1 += p1 * (float)c1.h[1] + p2 * (float)c2.h[1];
    u1 = u1n; u2 = u2n;
  }
  if (j < j1) {
    U1 c1; c1.u = u1;
    h2 sA = c1.h + xr0;
    sA = __builtin_elementwise_max(sA, sA * k02);
    h2 q = sA * at0;
    #pragma unroll
    for (int off = 1; off < 64; off <<= 1) q += shfl_xor_h2(q, off);
    float e1 = (float)q[0] + (float)q[1];
    if (__any(e1 > m + 8.f)) {
      float mn = fmaxf(m, e1);
      float c0 = __expf(m - mn);
      l *= c0; acc0 *= c0; acc1 *= c0;
      m = mn;
    }
    float p1 = __expf(e1 - m);
    l += p1;
    acc0 += p1 * (float)c1.h[0];
    acc1 += p1 * (float)c1.h[1];
  }
  float inv = 1.f / l;
  const float2 b2 = reinterpret_cast<const float2*>(bias)[l2];
  float2 o = make_float2(acc0 * inv + b2.x, acc1 * inv + b2.y);
  reinterpret_cast<float2*>(out)[(size_t)n * 64 + l2] = o;
}

extern "C" void kernel_launch(void* const* d_in, const int* in_sizes, int n_in,
                              void* d_out, int out_size, void* d_ws, size_t ws_size,
                              hipStream_t stream) {
  const float* x    = (const float*)d_in[0];
  const int*   ei   = (const int*)d_in[1];
  const float* Wl1  = (const float*)d_in[2];
  const float* Wr1  = (const float*)d_in[3];
  const float* att1 = (const float*)d_in[4];
  const float* b1   = (const float*)d_in[5];
  const float* bn1g = (const float*)d_in[6];
  const float* bn1b = (const float*)d_in[7];
  const float* bn1m = (const float*)d_in[8];
  const float* bn1v = (const float*)d_in[9];
  const float* Wl2  = (const float*)d_in[10];
  const float* Wr2  = (const float*)d_in[11];
  const float* att2 = (const float*)d_in[12];
  const float* b2   = (const float*)d_in[13];
  const float* bn2g = (const float*)d_in[14];
  const float* bn2b = (const float*)d_in[15];
  const float* bn2m = (const float*)d_in[16];
  const float* bn2v = (const float*)d_in[17];
  const float* Wl3  = (const float*)d_in[18];
  const float* Wr3  = (const float*)d_in[19];
  const float* att3 = (const float*)d_in[20];
  const float* b3   = (const float*)d_in[21];

  const int Hm   = in_sizes[5];          // 256
  const int Cout = in_sizes[21];         // 128
  const int Cin  = in_sizes[2] / Hm;     // 128
  const int N    = in_sizes[0] / Cin;    // 50000
  const int E    = in_sizes[1] / 2;      // 800000
  const int T    = E + N;

  _Float16* x16 = (_Float16*)d_ws;                 // N*Cin
  _Float16* h   = x16 + (size_t)N * Cin;           // N*Hm
  _Float16* xlr = h + (size_t)N * Hm;              // N*2*Hm
  _Float16* WT1 = xlr + (size_t)N * 2 * Hm;        // (2*Hm)*Cin
  _Float16* WT2 = WT1 + (size_t)2 * Hm * Cin;      // (2*Hm)*Hm
  _Float16* WT3 = WT2 + (size_t)2 * Hm * Hm;       // (2*Cout)*Hm
  int* deg    = (int*)(WT3 + (size_t)2 * Cout * Hm);
  int* offs   = deg + N;
  int* cursor = offs + N + 1;
  int* csr    = cursor + N;                        // T+4 entries (sentinels)
  int* bsum   = csr + T + 4;                       // nb entries

  const int nb = (N + 255) / 256;

  // --- CSR build by dst (hierarchical scan) ---
  k_zero_i32<<<(N + 255) / 256, 256, 0, stream>>>(deg, N);
  k_count<<<(T + 255) / 256, 256, 0, stream>>>(ei, E, N, deg);
  k_bsum<<<nb, 256, 0, stream>>>(deg, N, bsum);
  k_bscan<<<1, 1024, 0, stream>>>(bsum, nb, N, offs);
  k_boffs<<<nb, 256, 0, stream>>>(deg, N, bsum, offs, cursor);
  k_scatter<<<(T + 255) / 256, 256, 0, stream>>>(ei, E, N, cursor, csr);

  // --- convert inputs to fp16 ---
  int n2 = N * Cin / 2;
  k_f2h<<<(n2 + 255) / 256, 256, 0, stream>>>(x, (unsigned int*)x16, n2);
  k_prep_w<<<(2 * Hm * Cin + 255) / 256, 256, 0, stream>>>(Wl1, Wr1, Cin, Hm, WT1);
  k_prep_w<<<(2 * Hm * Hm + 255) / 256, 256, 0, stream>>>(Wl2, Wr2, Hm, Hm, WT2);
  k_prep_w<<<(2 * Cout * Hm + 255) / 256, 256, 0, stream>>>(Wl3, Wr3, Hm, Cout, WT3);

  const int mb = (N + 127) / 128;
  const int gb = (N + 1) / 2;

  // --- layer 1 ---
  k_hgemm<<<dim3(mb, 2 * Hm / 128), 256, 0, stream>>>(x16, WT1, xlr, N, 2 * Hm, Cin);
  k_gat4<<<gb, 128, 0, stream>>>(xlr, att1, b1, bn1g, bn1b, bn1m, bn1v, offs, csr, N, h);

  // --- layer 2 ---
  k_hgemm<<<dim3(mb, 2 * Hm / 128), 256, 0, stream>>>(h, WT2, xlr, N, 2 * Hm, Hm);
  k_gat4<<<gb, 128, 0, stream>>>(xlr, att2, b2, bn2g, bn2b, bn2m, bn2v, offs, csr, N, h);

  // --- layer 3 ---
  k_hgemm<<<dim3(mb, 2 * Cout / 128), 256, 0, stream>>>(h, WT3, xlr, N, 2 * Cout, Hm);
  k_gat1<<<gb, 128, 0, stream>>>(xlr, att3, b3, offs, csr, N, (float*)d_out);
}

// Round 5
// 378.870 us; speedup vs baseline: 3.1485x; 1.0695x over previous
//
#include <hip/hip_runtime.h>
#include <math.h>

#define NEG_SLOPE 0.2f
#define BN_EPS 1e-5f

typedef _Float16 f16x8 __attribute__((ext_vector_type(8)));
typedef float f32x4 __attribute__((ext_vector_type(4)));
typedef _Float16 h2 __attribute__((ext_vector_type(2)));

union F8 { f16x8 v; h2 h[4]; _Float16 s[8]; uint4 u; };

__device__ __forceinline__ void async_copy16(const void* g, void* l) {
  __builtin_amdgcn_global_load_lds(
      (const __attribute__((address_space(1))) void*)g,
      (__attribute__((address_space(3))) void*)l, 16, 0, 0);
}

__device__ __forceinline__ unsigned int pack2f(float a, float b) {
  union { unsigned int u; _Float16 h[2]; } c;
  c.h[0] = (_Float16)a; c.h[1] = (_Float16)b; return c.u;
}

__device__ __forceinline__ float fdot2f(h2 a, h2 b, float c) {
#if __has_builtin(__builtin_amdgcn_fdot2)
  return __builtin_amdgcn_fdot2(a, b, c, false);
#else
  return fmaf((float)a[0], (float)b[0], fmaf((float)a[1], (float)b[1], c));
#endif
}

// DPP butterfly add within quads (pure VALU, no LDS pipe).
// 0xB1 = quad_perm(1,0,3,2) -> xor 1 ; 0x4E = quad_perm(2,3,0,1) -> xor 2
template <int CTRL>
__device__ __forceinline__ float dpp_xadd(float x) {
  int yi = __builtin_amdgcn_mov_dpp(__builtin_bit_cast(int, x), CTRL, 0xF, 0xF, true);
  return x + __builtin_bit_cast(float, yi);
}

// ---------------- utility ----------------
__global__ void k_zero_i32(int* __restrict__ p, int n) {
  int i = blockIdx.x * blockDim.x + threadIdx.x;
  if (i < n) p[i] = 0;
}

__global__ void k_f2h(const float* __restrict__ in, unsigned int* __restrict__ out, int n2) {
  int i = blockIdx.x * blockDim.x + threadIdx.x;
  if (i < n2) {
    float2 v = reinterpret_cast<const float2*>(in)[i];
    out[i] = pack2f(v.x, v.y);
  }
}

// WT[c][k] = (c<Ch ? Wl[k][c] : Wr[k][c-Ch]) as fp16; WT is [2*Ch][K]
__global__ void k_prep_w(const float* __restrict__ Wl, const float* __restrict__ Wr,
                         int K, int Ch, _Float16* __restrict__ WT) {
  int i = blockIdx.x * blockDim.x + threadIdx.x;
  int total = 2 * Ch * K;
  if (i >= total) return;
  int c = i / K, k = i % K;
  float v = (c < Ch) ? Wl[(size_t)k * Ch + c] : Wr[(size_t)k * Ch + (c - Ch)];
  WT[i] = (_Float16)v;
}

// att -> fp16; BN folded: sc = g*rsqrt(rv+eps), sh = (bias - rm)*sc + bb
__global__ __launch_bounds__(256) void k_prep_misc(
    const float* __restrict__ att1, const float* __restrict__ att2, const float* __restrict__ att3,
    const float* __restrict__ b1, const float* __restrict__ g1, const float* __restrict__ bb1,
    const float* __restrict__ m1, const float* __restrict__ v1,
    const float* __restrict__ b2, const float* __restrict__ g2, const float* __restrict__ bb2,
    const float* __restrict__ m2, const float* __restrict__ v2,
    _Float16* __restrict__ a16_1, _Float16* __restrict__ a16_2, _Float16* __restrict__ a16_3,
    float* __restrict__ sc1, float* __restrict__ sh1,
    float* __restrict__ sc2, float* __restrict__ sh2) {
  int c = threadIdx.x;
  a16_1[c] = (_Float16)att1[c];
  a16_2[c] = (_Float16)att2[c];
  if (c < 128) a16_3[c] = (_Float16)att3[c];
  float s = g1[c] * rsqrtf(v1[c] + BN_EPS);
  sc1[c] = s; sh1[c] = (b1[c] - m1[c]) * s + bb1[c];
  s = g2[c] * rsqrtf(v2[c] + BN_EPS);
  sc2[c] = s; sh2[c] = (b2[c] - m2[c]) * s + bb2[c];
}

// ---------------- CSR build (group edges by dst) ----------------
__global__ void k_count(const int* __restrict__ ei, int E, int N, int* __restrict__ deg) {
  int e = blockIdx.x * blockDim.x + threadIdx.x;
  int T = E + N;
  if (e >= T) return;
  int d = (e < E) ? ei[E + e] : (e - E);
  atomicAdd(&deg[d], 1);
}

__global__ __launch_bounds__(256) void k_bsum(const int* __restrict__ deg, int N,
                                              int* __restrict__ bsum) {
  int t = threadIdx.x;
  int i = blockIdx.x * 256 + t;
  int v = (i < N) ? deg[i] : 0;
  #pragma unroll
  for (int off = 32; off > 0; off >>= 1) v += __shfl_xor(v, off, 64);
  __shared__ int ws[4];
  if ((t & 63) == 0) ws[t >> 6] = v;
  __syncthreads();
  if (t == 0) bsum[blockIdx.x] = ws[0] + ws[1] + ws[2] + ws[3];
}

__global__ __launch_bounds__(1024) void k_bscan(int* __restrict__ bsum, int nb, int N,
                                                int* __restrict__ offs) {
  int t = threadIdx.x;
  int lane = t & 63, w = t >> 6;
  int v = (t < nb) ? bsum[t] : 0;
  int val = v;
  #pragma unroll
  for (int off = 1; off < 64; off <<= 1) {
    int x = __shfl_up(val, off, 64);
    if (lane >= off) val += x;
  }
  __shared__ int ws[16];
  if (lane == 63) ws[w] = val;
  __syncthreads();
  if (w == 0) {
    int s = (lane < 16) ? ws[lane] : 0;
    #pragma unroll
    for (int off = 1; off < 16; off <<= 1) {
      int x = __shfl_up(s, off, 64);
      if (lane >= off) s += x;
    }
    if (lane < 16) ws[lane] = s;
  }
  __syncthreads();
  int excl = (w > 0 ? ws[w - 1] : 0) + val - v;
  if (t < nb) bsum[t] = excl;
  if (t == nb - 1) offs[N] = excl + v;
}

__global__ __launch_bounds__(256) void k_boffs(const int* __restrict__ deg, int N,
                                               const int* __restrict__ bpre,
                                               int* __restrict__ offs, int* __restrict__ cursor) {
  int t = threadIdx.x;
  int i = blockIdx.x * 256 + t;
  int lane = t & 63, w = t >> 6;
  int v = (i < N) ? deg[i] : 0;
  int val = v;
  #pragma unroll
  for (int off = 1; off < 64; off <<= 1) {
    int x = __shfl_up(val, off, 64);
    if (lane >= off) val += x;
  }
  __shared__ int ws[4];
  if (lane == 63) ws[w] = val;
  __syncthreads();
  int wo = 0;
  #pragma unroll
  for (int k = 0; k < 4; ++k) if (k < w) wo += ws[k];
  int excl = bpre[blockIdx.x] + wo + val - v;
  if (i < N) { offs[i] = excl; cursor[i] = excl; }
}

__global__ void k_scatter(const int* __restrict__ ei, int E, int N,
                          int* __restrict__ cursor, int* __restrict__ csr_src) {
  int e = blockIdx.x * blockDim.x + threadIdx.x;
  int T = E + N;
  if (e < 32) csr_src[T + e] = 0;  // sentinels for prefetch
  if (e >= T) return;
  int s, d;
  if (e < E) { s = ei[e]; d = ei[E + e]; } else { s = d = e - E; }
  int pos = atomicAdd(&cursor[d], 1);
  csr_src[pos] = s;
}

// ---------------- fp16 MFMA GEMM: C[M,Ntot] = A[M,K] @ BT[Ntot,K]^T ----------------
__global__ __launch_bounds__(256) void k_hgemm(const _Float16* __restrict__ A,
                                               const _Float16* __restrict__ BT,
                                               _Float16* __restrict__ C,
                                               int M, int Ntot, int K) {
  __shared__ _Float16 As[2][128 * 64];
  __shared__ _Float16 Bs[2][128 * 64];
  const int t = threadIdx.x;
  const int lane = t & 63, w = t >> 6;
  const int wr = w >> 1, wc = w & 1;
  const int bm0 = blockIdx.x * 128, bn0 = blockIdx.y * 128;
  f32x4 acc[4][4] = {};
  const int nkt = K >> 6;

  auto stage = [&](int b, int kt) {
    #pragma unroll
    for (int i = 0; i < 4; ++i) {
      int q = (i * 4 + w) * 64 + lane;
      int row = q >> 3, sl = q & 7;
      int ssrc = sl ^ (row & 7);
      int ga = bm0 + row; if (ga >= M) ga = M - 1;
      async_copy16(&A[(size_t)ga * K + kt * 64 + ssrc * 8], &As[b][q * 8]);
      async_copy16(&BT[(size_t)(bn0 + row) * K + kt * 64 + ssrc * 8], &Bs[b][q * 8]);
    }
  };

  stage(0, 0);
  for (int kt = 0; kt < nkt; ++kt) {
    int cur = kt & 1;
    if (kt + 1 < nkt) {
      stage(cur ^ 1, kt + 1);
      asm volatile("s_waitcnt vmcnt(8)" ::: "memory");
    } else {
      asm volatile("s_waitcnt vmcnt(0)" ::: "memory");
    }
    __builtin_amdgcn_s_barrier();
    #pragma unroll
    for (int ks = 0; ks < 2; ++ks) {
      f16x8 a[4], b[4];
      const int sl = ks * 4 + (lane >> 4);
      #pragma unroll
      for (int mi = 0; mi < 4; ++mi) {
        int row = wr * 64 + mi * 16 + (lane & 15);
        a[mi] = *(const f16x8*)&As[cur][(row * 8 + (sl ^ (row & 7))) * 8];
      }
      #pragma unroll
      for (int ni = 0; ni < 4; ++ni) {
        int row = wc * 64 + ni * 16 + (lane & 15);
        b[ni] = *(const f16x8*)&Bs[cur][(row * 8 + (sl ^ (row & 7))) * 8];
      }
      #pragma unroll
      for (int mi = 0; mi < 4; ++mi)
        #pragma unroll
        for (int ni = 0; ni < 4; ++ni)
          acc[mi][ni] = __builtin_amdgcn_mfma_f32_16x16x32_f16(a[mi], b[ni], acc[mi][ni], 0, 0, 0);
    }
    __builtin_amdgcn_s_barrier();
  }
  const int r0 = (lane >> 4) * 4;
  const int cc = lane & 15;
  #pragma unroll
  for (int mi = 0; mi < 4; ++mi) {
    #pragma unroll
    for (int r = 0; r < 4; ++r) {
      int row = bm0 + wr * 64 + mi * 16 + r0 + r;
      if (row >= M) continue;
      #pragma unroll
      for (int ni = 0; ni < 4; ++ni) {
        int col = bn0 + wc * 64 + ni * 16 + cc;
        C[(size_t)row * Ntot + col] = (_Float16)acc[mi][ni][r];
      }
    }
  }
}

// ---------------- fused GATv2 edge phase, H=4, F=64 (Hm=256) ----------------
// 1 wave/node (4 nodes per 256-thread block); 16 ch/lane -> 4 edges/iteration.
// quarter qi = lane>>4 owns edge slot; head = 4-lane group (sub>>2).
__global__ __launch_bounds__(256) void k_gat4(
    const _Float16* __restrict__ xlr,      // [N][512]: xl|xr
    const _Float16* __restrict__ att16,    // [256]
    const float* __restrict__ sc, const float* __restrict__ sh,   // folded BN (256)
    const int* __restrict__ offs, const int* __restrict__ csr,
    int N, _Float16* __restrict__ hout) {  // [N][256]
  const int n = blockIdx.x * 4 + (threadIdx.x >> 6);
  if (n >= N) return;
  const int lane = threadIdx.x & 63;
  const int sub = lane & 15;     // channel-slice id: ch [16*sub, 16*sub+16)
  const int qi = lane >> 4;      // edge slot within iteration

  const F8* xb = (const F8*)xlr;           // 16B units; row = 64 units
  const F8* ab = (const F8*)att16;

  F8 at0 = ab[2 * sub], at1 = ab[2 * sub + 1];
  F8 xr0 = xb[(size_t)n * 64 + 32 + 2 * sub];
  F8 xr1 = xb[(size_t)n * 64 + 32 + 2 * sub + 1];
  const h2 k02 = {(_Float16)NEG_SLOPE, (_Float16)NEG_SLOPE};

  const int j0 = offs[n], j1 = offs[n + 1];

  float m = -INFINITY, l = 0.f;
  float acc[16];
  #pragma unroll
  for (int i = 0; i < 16; ++i) acc[i] = 0.f;

  int sA = csr[j0 + qi];
  int sB = csr[j0 + 4 + qi];
  F8 v0 = xb[(size_t)sA * 64 + 2 * sub];
  F8 v1 = xb[(size_t)sA * 64 + 2 * sub + 1];

  for (int j = j0; j < j1; ) {
    F8 n0 = xb[(size_t)sB * 64 + 2 * sub];      // prefetch next 4 edges
    F8 n1 = xb[(size_t)sB * 64 + 2 * sub + 1];
    int sC = csr[j + 8 + qi];                    // 2-ahead csr (padded)

    float e = 0.f;
    #pragma unroll
    for (int r = 0; r < 4; ++r) {
      h2 s0 = v0.h[r] + xr0.h[r];
      s0 = __builtin_elementwise_max(s0, s0 * k02);
      e = fdot2f(s0, at0.h[r], e);
      h2 s1 = v1.h[r] + xr1.h[r];
      s1 = __builtin_elementwise_max(s1, s1 * k02);
      e = fdot2f(s1, at1.h[r], e);
    }
    e = dpp_xadd<0xB1>(e);   // xor 1
    e = dpp_xadd<0x4E>(e);   // xor 2  -> per-head e, uniform over head's 4 lanes
    if (j + qi >= j1) e = -1e30f;               // tail mask -> p underflows to 0

    if (__any(e > m + 8.f)) {                   // defer-max (rare)
      float mc = fmaxf(m, e);
      mc = fmaxf(mc, __shfl_xor(mc, 16, 64));   // consistent across quarters
      mc = fmaxf(mc, __shfl_xor(mc, 32, 64));
      float c0 = __expf(m - mc);
      l *= c0;
      #pragma unroll
      for (int i = 0; i < 16; ++i) acc[i] *= c0;
      m = mc;
    }
    float p = __expf(e - m);
    l += p;
    #pragma unroll
    for (int i = 0; i < 8; ++i) acc[i] = fmaf(p, (float)v0.s[i], acc[i]);
    #pragma unroll
    for (int i = 0; i < 8; ++i) acc[8 + i] = fmaf(p, (float)v1.s[i], acc[8 + i]);
    v0 = n0; v1 = n1; sB = sC; j += 4;
  }
  // merge quarters (m uniform per head) -> plain sums
  l += __shfl_xor(l, 16, 64);
  l += __shfl_xor(l, 32, 64);
  #pragma unroll
  for (int i = 0; i < 16; ++i) {
    acc[i] += __shfl_xor(acc[i], 16, 64);
    acc[i] += __shfl_xor(acc[i], 32, 64);
  }
  if (qi == 0) {
    float inv = 1.f / l;
    const float4* sc4 = (const float4*)sc;
    const float4* sh4 = (const float4*)sh;
    float ov[16];
    #pragma unroll
    for (int k = 0; k < 4; ++k) {
      float4 s4 = sc4[4 * sub + k], t4 = sh4[4 * sub + k];
      ov[4 * k + 0] = acc[4 * k + 0] * inv * s4.x + t4.x;
      ov[4 * k + 1] = acc[4 * k + 1] * inv * s4.y + t4.y;
      ov[4 * k + 2] = acc[4 * k + 2] * inv * s4.z + t4.z;
      ov[4 * k + 3] = acc[4 * k + 3] * inv * s4.w + t4.w;
    }
    #pragma unroll
    for (int i = 0; i < 16; ++i) ov[i] = ov[i] > 0.f ? ov[i] : (__expf(ov[i]) - 1.f);
    F8 o0, o1;
    #pragma unroll
    for (int i = 0; i < 8; ++i) { o0.s[i] = (_Float16)ov[i]; o1.s[i] = (_Float16)ov[8 + i]; }
    F8* ob = (F8*)hout;                         // row = 32 units
    ob[(size_t)n * 32 + 2 * sub] = o0;
    ob[(size_t)n * 32 + 2 * sub + 1] = o1;
  }
}

// ---------------- fused GATv2 edge phase, H=1, F=128 (layer 3) ----------------
// 16 ch/lane -> 8 lanes/edge -> 8 edges/iteration; head = all 8 lanes.
__global__ __launch_bounds__(256) void k_gat1(
    const _Float16* __restrict__ xlr,      // [N][256]: xl|xr
    const _Float16* __restrict__ att16,    // [128]
    const float* __restrict__ bias,        // [128]
    const int* __restrict__ offs, const int* __restrict__ csr,
    int N, float* __restrict__ out) {      // [N][128] fp32
  const int n = blockIdx.x * 4 + (threadIdx.x >> 6);
  if (n >= N) return;
  const int lane = threadIdx.x & 63;
  const int sub = lane & 7;      // ch slice [16*sub, +16)
  const int gi = lane >> 3;      // edge slot 0..7

  const F8* xb = (const F8*)xlr;           // row = 32 units
  const F8* ab = (const F8*)att16;
  F8 at0 = ab[2 * sub], at1 = ab[2 * sub + 1];
  F8 xr0 = xb[(size_t)n * 32 + 16 + 2 * sub];
  F8 xr1 = xb[(size_t)n * 32 + 16 + 2 * sub + 1];
  const h2 k02 = {(_Float16)NEG_SLOPE, (_Float16)NEG_SLOPE};

  const int j0 = offs[n], j1 = offs[n + 1];
  float m = -INFINITY, l = 0.f;
  float acc[16];
  #pragma unroll
  for (int i = 0; i < 16; ++i) acc[i] = 0.f;

  int sA = csr[j0 + gi];
  int sB = csr[j0 + 8 + gi];
  F8 v0 = xb[(size_t)sA * 32 + 2 * sub];
  F8 v1 = xb[(size_t)sA * 32 + 2 * sub + 1];

  for (int j = j0; j < j1; ) {
    F8 n0 = xb[(size_t)sB * 32 + 2 * sub];
    F8 n1 = xb[(size_t)sB * 32 + 2 * sub + 1];
    int sC = csr[j + 16 + gi];

    float e = 0.f;
    #pragma unroll
    for (int r = 0; r < 4; ++r) {
      h2 s0 = v0.h[r] + xr0.h[r];
      s0 = __builtin_elementwise_max(s0, s0 * k02);
      e = fdot2f(s0, at0.h[r], e);
      h2 s1 = v1.h[r] + xr1.h[r];
      s1 = __builtin_elementwise_max(s1, s1 * k02);
      e = fdot2f(s1, at1.h[r], e);
    }
    e = dpp_xadd<0xB1>(e);
    e = dpp_xadd<0x4E>(e);
    e += __shfl_xor(e, 4, 64);                  // full 8-lane (128 ch) sum
    if (j + gi >= j1) e = -1e30f;

    if (__any(e > m + 8.f)) {
      float mc = fmaxf(m, e);
      mc = fmaxf(mc, __shfl_xor(mc, 8, 64));
      mc = fmaxf(mc, __shfl_xor(mc, 16, 64));
      mc = fmaxf(mc, __shfl_xor(mc, 32, 64));
      float c0 = __expf(m - mc);
      l *= c0;
      #pragma unroll
      for (int i = 0; i < 16; ++i) acc[i] *= c0;
      m = mc;
    }
    float p = __expf(e - m);
    l += p;
    #pragma unroll
    for (int i = 0; i < 8; ++i) acc[i] = fmaf(p, (float)v0.s[i], acc[i]);
    #pragma unroll
    for (int i = 0; i < 8; ++i) acc[8 + i] = fmaf(p, (float)v1.s[i], acc[8 + i]);
    v0 = n0; v1 = n1; sB = sC; j += 8;
  }
  l += __shfl_xor(l, 8, 64);
  l += __shfl_xor(l, 16, 64);
  l += __shfl_xor(l, 32, 64);
  #pragma unroll
  for (int i = 0; i < 16; ++i) {
    acc[i] += __shfl_xor(acc[i], 8, 64);
    acc[i] += __shfl_xor(acc[i], 16, 64);
    acc[i] += __shfl_xor(acc[i], 32, 64);
  }
  if (gi == 0) {
    float inv = 1.f / l;
    const float4* b4 = (const float4*)bias;
    float4* ob = (float4*)out;                  // row = 32 float4
    #pragma unroll
    for (int k = 0; k < 4; ++k) {
      float4 bb = b4[4 * sub + k];
      float4 o;
      o.x = acc[4 * k + 0] * inv + bb.x;
      o.y = acc[4 * k + 1] * inv + bb.y;
      o.z = acc[4 * k + 2] * inv + bb.z;
      o.w = acc[4 * k + 3] * inv + bb.w;
      ob[(size_t)n * 32 + 4 * sub + k] = o;
    }
  }
}

extern "C" void kernel_launch(void* const* d_in, const int* in_sizes, int n_in,
                              void* d_out, int out_size, void* d_ws, size_t ws_size,
                              hipStream_t stream) {
  const float* x    = (const float*)d_in[0];
  const int*   ei   = (const int*)d_in[1];
  const float* Wl1  = (const float*)d_in[2];
  const float* Wr1  = (const float*)d_in[3];
  const float* att1 = (const float*)d_in[4];
  const float* b1   = (const float*)d_in[5];
  const float* bn1g = (const float*)d_in[6];
  const float* bn1b = (const float*)d_in[7];
  const float* bn1m = (const float*)d_in[8];
  const float* bn1v = (const float*)d_in[9];
  const float* Wl2  = (const float*)d_in[10];
  const float* Wr2  = (const float*)d_in[11];
  const float* att2 = (const float*)d_in[12];
  const float* b2   = (const float*)d_in[13];
  const float* bn2g = (const float*)d_in[14];
  const float* bn2b = (const float*)d_in[15];
  const float* bn2m = (const float*)d_in[16];
  const float* bn2v = (const float*)d_in[17];
  const float* Wl3  = (const float*)d_in[18];
  const float* Wr3  = (const float*)d_in[19];
  const float* att3 = (const float*)d_in[20];
  const float* b3   = (const float*)d_in[21];

  const int Hm   = in_sizes[5];          // 256
  const int Cout = in_sizes[21];         // 128
  const int Cin  = in_sizes[2] / Hm;     // 128
  const int N    = in_sizes[0] / Cin;    // 50000
  const int E    = in_sizes[1] / 2;      // 800000
  const int T    = E + N;

  _Float16* x16 = (_Float16*)d_ws;                 // N*Cin
  _Float16* h   = x16 + (size_t)N * Cin;           // N*Hm
  _Float16* xlr = h + (size_t)N * Hm;              // N*2*Hm
  _Float16* WT1 = xlr + (size_t)N * 2 * Hm;        // (2*Hm)*Cin
  _Float16* WT2 = WT1 + (size_t)2 * Hm * Cin;      // (2*Hm)*Hm
  _Float16* WT3 = WT2 + (size_t)2 * Hm * Hm;       // (2*Cout)*Hm
  _Float16* a16_1 = WT3 + (size_t)2 * Cout * Hm;   // 256
  _Float16* a16_2 = a16_1 + 256;                   // 256
  _Float16* a16_3 = a16_2 + 256;                   // 128
  float* sc1 = (float*)(a16_3 + 128);              // 256
  float* sh1 = sc1 + 256;
  float* sc2 = sh1 + 256;
  float* sh2 = sc2 + 256;
  int* deg    = (int*)(sh2 + 256);
  int* offs   = deg + N;
  int* cursor = offs + N + 1;
  int* csr    = cursor + N;                        // T+32 entries (sentinels)
  int* bsum   = csr + T + 32;

  const int nb = (N + 255) / 256;

  // --- CSR build by dst (hierarchical scan) ---
  k_zero_i32<<<(N + 255) / 256, 256, 0, stream>>>(deg, N);
  k_count<<<(T + 255) / 256, 256, 0, stream>>>(ei, E, N, deg);
  k_bsum<<<nb, 256, 0, stream>>>(deg, N, bsum);
  k_bscan<<<1, 1024, 0, stream>>>(bsum, nb, N, offs);
  k_boffs<<<nb, 256, 0, stream>>>(deg, N, bsum, offs, cursor);
  k_scatter<<<(T + 255) / 256, 256, 0, stream>>>(ei, E, N, cursor, csr);

  // --- convert inputs to fp16 / fold BN ---
  int n2 = N * Cin / 2;
  k_f2h<<<(n2 + 255) / 256, 256, 0, stream>>>(x, (unsigned int*)x16, n2);
  k_prep_w<<<(2 * Hm * Cin + 255) / 256, 256, 0, stream>>>(Wl1, Wr1, Cin, Hm, WT1);
  k_prep_w<<<(2 * Hm * Hm + 255) / 256, 256, 0, stream>>>(Wl2, Wr2, Hm, Hm, WT2);
  k_prep_w<<<(2 * Cout * Hm + 255) / 256, 256, 0, stream>>>(Wl3, Wr3, Hm, Cout, WT3);
  k_prep_misc<<<1, 256, 0, stream>>>(att1, att2, att3,
                                     b1, bn1g, bn1b, bn1m, bn1v,
                                     b2, bn2g, bn2b, bn2m, bn2v,
                                     a16_1, a16_2, a16_3, sc1, sh1, sc2, sh2);

  const int mb = (N + 127) / 128;
  const int gb = (N + 3) / 4;

  // --- layer 1 ---
  k_hgemm<<<dim3(mb, 2 * Hm / 128), 256, 0, stream>>>(x16, WT1, xlr, N, 2 * Hm, Cin);
  k_gat4<<<gb, 256, 0, stream>>>(xlr, a16_1, sc1, sh1, offs, csr, N, h);

  // --- layer 2 ---
  k_hgemm<<<dim3(mb, 2 * Hm / 128), 256, 0, stream>>>(h, WT2, xlr, N, 2 * Hm, Hm);
  k_gat4<<<gb, 256, 0, stream>>>(xlr, a16_2, sc2, sh2, offs, csr, N, h);

  // --- layer 3 ---
  k_hgemm<<<dim3(mb, 2 * Cout / 128), 256, 0, stream>>>(h, WT3, xlr, N, 2 * Cout, Hm);
  k_gat1<<<gb, 256, 0, stream>>>(xlr, a16_3, b3, offs, csr, N, (float*)d_out);
}

// Round 6
// 377.770 us; speedup vs baseline: 3.1576x; 1.0029x over previous
//
#include <hip/hip_runtime.h>
#include <math.h>

#define NEG_SLOPE 0.2f
#define BN_EPS 1e-5f
#define LOG2E 1.44269504f

typedef _Float16 f16x8 __attribute__((ext_vector_type(8)));
typedef float f32x4 __attribute__((ext_vector_type(4)));
typedef _Float16 h2 __attribute__((ext_vector_type(2)));

union F8 { f16x8 v; h2 h[4]; _Float16 s[8]; uint4 u; };

__device__ __forceinline__ void async_copy16(const void* g, void* l) {
  __builtin_amdgcn_global_load_lds(
      (const __attribute__((address_space(1))) void*)g,
      (__attribute__((address_space(3))) void*)l, 16, 0, 0);
}

__device__ __forceinline__ unsigned int pack2f(float a, float b) {
  union { unsigned int u; _Float16 h[2]; } c;
  c.h[0] = (_Float16)a; c.h[1] = (_Float16)b; return c.u;
}

__device__ __forceinline__ float fdot2f(h2 a, h2 b, float c) {
#if __has_builtin(__builtin_amdgcn_fdot2)
  return __builtin_amdgcn_fdot2(a, b, c, false);
#else
  return fmaf((float)a[0], (float)b[0], fmaf((float)a[1], (float)b[1], c));
#endif
}

// DPP butterfly add within quads (pure VALU, no LDS pipe).
template <int CTRL>
__device__ __forceinline__ float dpp_xadd(float x) {
  int yi = __builtin_amdgcn_mov_dpp(__builtin_bit_cast(int, x), CTRL, 0xF, 0xF, true);
  return x + __builtin_bit_cast(float, yi);
}

// ---------------- utility ----------------
__global__ void k_zero_i32(int* __restrict__ p, int n) {
  int i = blockIdx.x * blockDim.x + threadIdx.x;
  if (i < n) p[i] = 0;
}

__global__ void k_f2h(const float* __restrict__ in, unsigned int* __restrict__ out, int n2) {
  int i = blockIdx.x * blockDim.x + threadIdx.x;
  if (i < n2) {
    float2 v = reinterpret_cast<const float2*>(in)[i];
    out[i] = pack2f(v.x, v.y);
  }
}

// all three weight preps in one launch. WT[c][k] layout, Wl|Wr concat.
__global__ __launch_bounds__(256) void k_prep_w3(
    const float* __restrict__ Wl1, const float* __restrict__ Wr1,
    const float* __restrict__ Wl2, const float* __restrict__ Wr2,
    const float* __restrict__ Wl3, const float* __restrict__ Wr3,
    int Cin, int Hm, int Cout,
    _Float16* __restrict__ WT1, _Float16* __restrict__ WT2, _Float16* __restrict__ WT3) {
  int i = blockIdx.x * 256 + threadIdx.x;
  int n1 = 2 * Hm * Cin, n2 = 2 * Hm * Hm, n3 = 2 * Cout * Hm;
  if (i < n1) {
    int c = i / Cin, k = i % Cin;
    float v = (c < Hm) ? Wl1[(size_t)k * Hm + c] : Wr1[(size_t)k * Hm + (c - Hm)];
    WT1[i] = (_Float16)v;
    return;
  }
  i -= n1;
  if (i < n2) {
    int c = i / Hm, k = i % Hm;
    float v = (c < Hm) ? Wl2[(size_t)k * Hm + c] : Wr2[(size_t)k * Hm + (c - Hm)];
    WT2[i] = (_Float16)v;
    return;
  }
  i -= n2;
  if (i < n3) {
    int c = i / Hm, k = i % Hm;
    float v = (c < Cout) ? Wl3[(size_t)k * Cout + c] : Wr3[(size_t)k * Cout + (c - Cout)];
    WT3[i] = (_Float16)v;
  }
}

// att -> fp16 scaled by log2(e) (softmax in exp2 domain); BN folded.
__global__ __launch_bounds__(256) void k_prep_misc(
    const float* __restrict__ att1, const float* __restrict__ att2, const float* __restrict__ att3,
    const float* __restrict__ b1, const float* __restrict__ g1, const float* __restrict__ bb1,
    const float* __restrict__ m1, const float* __restrict__ v1,
    const float* __restrict__ b2, const float* __restrict__ g2, const float* __restrict__ bb2,
    const float* __restrict__ m2, const float* __restrict__ v2,
    _Float16* __restrict__ a16_1, _Float16* __restrict__ a16_2, _Float16* __restrict__ a16_3,
    float* __restrict__ sc1, float* __restrict__ sh1,
    float* __restrict__ sc2, float* __restrict__ sh2) {
  int c = threadIdx.x;
  a16_1[c] = (_Float16)(att1[c] * LOG2E);
  a16_2[c] = (_Float16)(att2[c] * LOG2E);
  if (c < 128) a16_3[c] = (_Float16)(att3[c] * LOG2E);
  float s = g1[c] * rsqrtf(v1[c] + BN_EPS);
  sc1[c] = s; sh1[c] = (b1[c] - m1[c]) * s + bb1[c];
  s = g2[c] * rsqrtf(v2[c] + BN_EPS);
  sc2[c] = s; sh2[c] = (b2[c] - m2[c]) * s + bb2[c];
}

// ---------------- CSR build (group edges by dst) ----------------
__global__ void k_count(const int* __restrict__ ei, int E, int N, int* __restrict__ deg) {
  int e = blockIdx.x * blockDim.x + threadIdx.x;
  int T = E + N;
  if (e >= T) return;
  int d = (e < E) ? ei[E + e] : (e - E);
  atomicAdd(&deg[d], 1);
}

__global__ __launch_bounds__(256) void k_bsum(const int* __restrict__ deg, int N,
                                              int* __restrict__ bsum) {
  int t = threadIdx.x;
  int i = blockIdx.x * 256 + t;
  int v = (i < N) ? deg[i] : 0;
  #pragma unroll
  for (int off = 32; off > 0; off >>= 1) v += __shfl_xor(v, off, 64);
  __shared__ int ws[4];
  if ((t & 63) == 0) ws[t >> 6] = v;
  __syncthreads();
  if (t == 0) bsum[blockIdx.x] = ws[0] + ws[1] + ws[2] + ws[3];
}

__global__ __launch_bounds__(1024) void k_bscan(int* __restrict__ bsum, int nb, int N,
                                                int* __restrict__ offs) {
  int t = threadIdx.x;
  int lane = t & 63, w = t >> 6;
  int v = (t < nb) ? bsum[t] : 0;
  int val = v;
  #pragma unroll
  for (int off = 1; off < 64; off <<= 1) {
    int x = __shfl_up(val, off, 64);
    if (lane >= off) val += x;
  }
  __shared__ int ws[16];
  if (lane == 63) ws[w] = val;
  __syncthreads();
  if (w == 0) {
    int s = (lane < 16) ? ws[lane] : 0;
    #pragma unroll
    for (int off = 1; off < 16; off <<= 1) {
      int x = __shfl_up(s, off, 64);
      if (lane >= off) s += x;
    }
    if (lane < 16) ws[lane] = s;
  }
  __syncthreads();
  int excl = (w > 0 ? ws[w - 1] : 0) + val - v;
  if (t < nb) bsum[t] = excl;
  if (t == nb - 1) offs[N] = excl + v;
}

__global__ __launch_bounds__(256) void k_boffs(const int* __restrict__ deg, int N,
                                               const int* __restrict__ bpre,
                                               int* __restrict__ offs, int* __restrict__ cursor) {
  int t = threadIdx.x;
  int i = blockIdx.x * 256 + t;
  int lane = t & 63, w = t >> 6;
  int v = (i < N) ? deg[i] : 0;
  int val = v;
  #pragma unroll
  for (int off = 1; off < 64; off <<= 1) {
    int x = __shfl_up(val, off, 64);
    if (lane >= off) val += x;
  }
  __shared__ int ws[4];
  if (lane == 63) ws[w] = val;
  __syncthreads();
  int wo = 0;
  #pragma unroll
  for (int k = 0; k < 4; ++k) if (k < w) wo += ws[k];
  int excl = bpre[blockIdx.x] + wo + val - v;
  if (i < N) { offs[i] = excl; cursor[i] = excl; }
}

__global__ void k_scatter(const int* __restrict__ ei, int E, int N,
                          int* __restrict__ cursor, int* __restrict__ csr_src) {
  int e = blockIdx.x * blockDim.x + threadIdx.x;
  int T = E + N;
  if (e < 32) csr_src[T + e] = 0;  // sentinels for prefetch
  if (e >= T) return;
  int s, d;
  if (e < E) { s = ei[e]; d = ei[E + e]; } else { s = d = e - E; }
  int pos = atomicAdd(&cursor[d], 1);
  csr_src[pos] = s;
}

// ---------------- fp16 MFMA GEMM: C[M,Ntot] = A[M,K] @ BT[Ntot,K]^T ----------------
// 128x256 tile, BK=64, 512 threads (8 waves, 2x4 of 64x64). Counted-vmcnt pipeline.
__global__ __launch_bounds__(512) void k_hgemm(const _Float16* __restrict__ A,
                                               const _Float16* __restrict__ BT,
                                               _Float16* __restrict__ C,
                                               int M, int Ntot, int K) {
  __shared__ _Float16 As[2][128 * 64];
  __shared__ _Float16 Bs[2][256 * 64];
  const int t = threadIdx.x;
  const int lane = t & 63, w = t >> 6;
  const int wr = w >> 2, wc = w & 3;
  const int bm0 = blockIdx.x * 128, bn0 = blockIdx.y * 256;
  f32x4 acc[4][4] = {};
  const int nkt = K >> 6;

  auto stage = [&](int b, int kt) {
    #pragma unroll
    for (int i = 0; i < 2; ++i) {
      int q = i * 512 + t;                 // A: 1024 slots
      int row = q >> 3, sl = q & 7;
      int ssrc = sl ^ (row & 7);
      int ga = bm0 + row; if (ga >= M) ga = M - 1;
      async_copy16(&A[(size_t)ga * K + kt * 64 + ssrc * 8], &As[b][q * 8]);
    }
    #pragma unroll
    for (int i = 0; i < 4; ++i) {
      int q = i * 512 + t;                 // B: 2048 slots
      int row = q >> 3, sl = q & 7;
      int ssrc = sl ^ (row & 7);
      async_copy16(&BT[(size_t)(bn0 + row) * K + kt * 64 + ssrc * 8], &Bs[b][q * 8]);
    }
  };

  stage(0, 0);
  for (int kt = 0; kt < nkt; ++kt) {
    int cur = kt & 1;
    if (kt + 1 < nkt) {
      stage(cur ^ 1, kt + 1);
      asm volatile("s_waitcnt vmcnt(6)" ::: "memory");   // prev stage drained
    } else {
      asm volatile("s_waitcnt vmcnt(0)" ::: "memory");
    }
    __builtin_amdgcn_s_barrier();
    #pragma unroll
    for (int ks = 0; ks < 2; ++ks) {
      f16x8 a[4], b[4];
      const int sl = ks * 4 + (lane >> 4);
      #pragma unroll
      for (int mi = 0; mi < 4; ++mi) {
        int row = wr * 64 + mi * 16 + (lane & 15);
        a[mi] = *(const f16x8*)&As[cur][(row * 8 + (sl ^ (row & 7))) * 8];
      }
      #pragma unroll
      for (int ni = 0; ni < 4; ++ni) {
        int row = wc * 64 + ni * 16 + (lane & 15);
        b[ni] = *(const f16x8*)&Bs[cur][(row * 8 + (sl ^ (row & 7))) * 8];
      }
      #pragma unroll
      for (int mi = 0; mi < 4; ++mi)
        #pragma unroll
        for (int ni = 0; ni < 4; ++ni)
          acc[mi][ni] = __builtin_amdgcn_mfma_f32_16x16x32_f16(a[mi], b[ni], acc[mi][ni], 0, 0, 0);
    }
    __builtin_amdgcn_s_barrier();
  }
  const int r0 = (lane >> 4) * 4;
  const int cc = lane & 15;
  #pragma unroll
  for (int mi = 0; mi < 4; ++mi) {
    #pragma unroll
    for (int r = 0; r < 4; ++r) {
      int row = bm0 + wr * 64 + mi * 16 + r0 + r;
      if (row >= M) continue;
      #pragma unroll
      for (int ni = 0; ni < 4; ++ni) {
        int col = bn0 + wc * 64 + ni * 16 + cc;
        C[(size_t)row * Ntot + col] = (_Float16)acc[mi][ni][r];
      }
    }
  }
}

// ---------------- fused GATv2 edge phase, H=4, F=64 (Hm=256) ----------------
// 1 wave/node; 16 ch/lane -> 4 edges/iteration; 32-bit SADDR offsets; exp2 softmax.
__global__ __launch_bounds__(256) void k_gat4(
    const _Float16* __restrict__ xlr,      // [N][512]: xl|xr, row = 1024 B
    const _Float16* __restrict__ att16,    // [256], pre-scaled by log2e
    const float* __restrict__ sc, const float* __restrict__ sh,
    const int* __restrict__ offs, const int* __restrict__ csr,
    int N, _Float16* __restrict__ hout) {  // [N][256]
  const int n = blockIdx.x * 4 + (threadIdx.x >> 6);
  if (n >= N) return;
  const int lane = threadIdx.x & 63;
  const int sub = lane & 15;
  const int qi = lane >> 4;
  const unsigned subB = (unsigned)sub << 5;
  const char* __restrict__ xc = (const char*)xlr;

  F8 at0, at1, xr0, xr1;
  at0.u = *(const uint4*)((const char*)att16 + subB);
  at1.u = *(const uint4*)((const char*)att16 + subB + 16);
  {
    unsigned xro = (unsigned)n * 1024u + 512u + subB;
    xr0.u = *(const uint4*)(xc + xro);
    xr1.u = *(const uint4*)(xc + xro + 16);
  }
  const h2 k02 = {(_Float16)NEG_SLOPE, (_Float16)NEG_SLOPE};
  const int j0 = offs[n], j1 = offs[n + 1];

  float m = -INFINITY, l = 0.f;
  float acc[16];
  #pragma unroll
  for (int i = 0; i < 16; ++i) acc[i] = 0.f;

  unsigned oA = (unsigned)csr[j0 + qi] * 1024u + subB;
  unsigned oB = (unsigned)csr[j0 + 4 + qi] * 1024u + subB;
  F8 v0, v1;
  v0.u = *(const uint4*)(xc + oA);
  v1.u = *(const uint4*)(xc + oA + 16);

  for (int j = j0; j < j1; j += 4) {
    F8 n0, n1;
    n0.u = *(const uint4*)(xc + oB);          // prefetch next 4 edges
    n1.u = *(const uint4*)(xc + oB + 16);
    oB = (unsigned)csr[j + 8 + qi] * 1024u + subB;

    float e = 0.f;
    #pragma unroll
    for (int r = 0; r < 4; ++r) {
      h2 s0 = v0.h[r] + xr0.h[r];
      s0 = __builtin_elementwise_max(s0, s0 * k02);
      e = fdot2f(s0, at0.h[r], e);
      h2 s1 = v1.h[r] + xr1.h[r];
      s1 = __builtin_elementwise_max(s1, s1 * k02);
      e = fdot2f(s1, at1.h[r], e);
    }
    e = dpp_xadd<0xB1>(e);
    e = dpp_xadd<0x4E>(e);
    if (j + qi >= j1) e = -1e30f;             // tail mask

    if (__any(e > m + 11.5f)) {               // defer-max (log2 units)
      float mc = fmaxf(m, e);
      mc = fmaxf(mc, __shfl_xor(mc, 16, 64));
      mc = fmaxf(mc, __shfl_xor(mc, 32, 64));
      float c0 = exp2f(m - mc);
      l *= c0;
      #pragma unroll
      for (int i = 0; i < 16; ++i) acc[i] *= c0;
      m = mc;
    }
    float p = exp2f(e - m);
    l += p;
    #pragma unroll
    for (int i = 0; i < 8; ++i) acc[i] = fmaf(p, (float)v0.s[i], acc[i]);
    #pragma unroll
    for (int i = 0; i < 8; ++i) acc[8 + i] = fmaf(p, (float)v1.s[i], acc[8 + i]);
    v0 = n0; v1 = n1;
  }
  // merge quarters
  l += __shfl_xor(l, 16, 64);
  l += __shfl_xor(l, 32, 64);
  #pragma unroll
  for (int i = 0; i < 16; ++i) {
    acc[i] += __shfl_xor(acc[i], 16, 64);
    acc[i] += __shfl_xor(acc[i], 32, 64);
  }
  if (qi == 0) {
    float inv = 1.f / l;
    const float4* sc4 = (const float4*)sc;
    const float4* sh4 = (const float4*)sh;
    float ov[16];
    #pragma unroll
    for (int k = 0; k < 4; ++k) {
      float4 s4 = sc4[4 * sub + k], t4 = sh4[4 * sub + k];
      ov[4 * k + 0] = acc[4 * k + 0] * inv * s4.x + t4.x;
      ov[4 * k + 1] = acc[4 * k + 1] * inv * s4.y + t4.y;
      ov[4 * k + 2] = acc[4 * k + 2] * inv * s4.z + t4.z;
      ov[4 * k + 3] = acc[4 * k + 3] * inv * s4.w + t4.w;
    }
    #pragma unroll
    for (int i = 0; i < 16; ++i) ov[i] = ov[i] > 0.f ? ov[i] : (__expf(ov[i]) - 1.f);
    F8 o0, o1;
    #pragma unroll
    for (int i = 0; i < 8; ++i) { o0.s[i] = (_Float16)ov[i]; o1.s[i] = (_Float16)ov[8 + i]; }
    F8* ob = (F8*)hout;
    ob[(size_t)n * 32 + 2 * sub] = o0;
    ob[(size_t)n * 32 + 2 * sub + 1] = o1;
  }
}

// ---------------- fused GATv2 edge phase, H=1, F=128 (layer 3) ----------------
__global__ __launch_bounds__(256) void k_gat1(
    const _Float16* __restrict__ xlr,      // [N][256]: xl|xr, row = 512 B
    const _Float16* __restrict__ att16,    // [128], pre-scaled by log2e
    const float* __restrict__ bias,        // [128]
    const int* __restrict__ offs, const int* __restrict__ csr,
    int N, float* __restrict__ out) {      // [N][128] fp32
  const int n = blockIdx.x * 4 + (threadIdx.x >> 6);
  if (n >= N) return;
  const int lane = threadIdx.x & 63;
  const int sub = lane & 7;
  const int gi = lane >> 3;
  const unsigned subB = (unsigned)sub << 5;
  const char* __restrict__ xc = (const char*)xlr;

  F8 at0, at1, xr0, xr1;
  at0.u = *(const uint4*)((const char*)att16 + subB);
  at1.u = *(const uint4*)((const char*)att16 + subB + 16);
  {
    unsigned xro = (unsigned)n * 512u + 256u + subB;
    xr0.u = *(const uint4*)(xc + xro);
    xr1.u = *(const uint4*)(xc + xro + 16);
  }
  const h2 k02 = {(_Float16)NEG_SLOPE, (_Float16)NEG_SLOPE};
  const int j0 = offs[n], j1 = offs[n + 1];

  float m = -INFINITY, l = 0.f;
  float acc[16];
  #pragma unroll
  for (int i = 0; i < 16; ++i) acc[i] = 0.f;

  unsigned oA = (unsigned)csr[j0 + gi] * 512u + subB;
  unsigned oB = (unsigned)csr[j0 + 8 + gi] * 512u + subB;
  F8 v0, v1;
  v0.u = *(const uint4*)(xc + oA);
  v1.u = *(const uint4*)(xc + oA + 16);

  for (int j = j0; j < j1; j += 8) {
    F8 n0, n1;
    n0.u = *(const uint4*)(xc + oB);
    n1.u = *(const uint4*)(xc + oB + 16);
    oB = (unsigned)csr[j + 16 + gi] * 512u + subB;

    float e = 0.f;
    #pragma unroll
    for (int r = 0; r < 4; ++r) {
      h2 s0 = v0.h[r] + xr0.h[r];
      s0 = __builtin_elementwise_max(s0, s0 * k02);
      e = fdot2f(s0, at0.h[r], e);
      h2 s1 = v1.h[r] + xr1.h[r];
      s1 = __builtin_elementwise_max(s1, s1 * k02);
      e = fdot2f(s1, at1.h[r], e);
    }
    e = dpp_xadd<0xB1>(e);
    e = dpp_xadd<0x4E>(e);
    e += __shfl_xor(e, 4, 64);
    if (j + gi >= j1) e = -1e30f;

    if (__any(e > m + 11.5f)) {
      float mc = fmaxf(m, e);
      mc = fmaxf(mc, __shfl_xor(mc, 8, 64));
      mc = fmaxf(mc, __shfl_xor(mc, 16, 64));
      mc = fmaxf(mc, __shfl_xor(mc, 32, 64));
      float c0 = exp2f(m - mc);
      l *= c0;
      #pragma unroll
      for (int i = 0; i < 16; ++i) acc[i] *= c0;
      m = mc;
    }
    float p = exp2f(e - m);
    l += p;
    #pragma unroll
    for (int i = 0; i < 8; ++i) acc[i] = fmaf(p, (float)v0.s[i], acc[i]);
    #pragma unroll
    for (int i = 0; i < 8; ++i) acc[8 + i] = fmaf(p, (float)v1.s[i], acc[8 + i]);
    v0 = n0; v1 = n1;
  }
  l += __shfl_xor(l, 8, 64);
  l += __shfl_xor(l, 16, 64);
  l += __shfl_xor(l, 32, 64);
  #pragma unroll
  for (int i = 0; i < 16; ++i) {
    acc[i] += __shfl_xor(acc[i], 8, 64);
    acc[i] += __shfl_xor(acc[i], 16, 64);
    acc[i] += __shfl_xor(acc[i], 32, 64);
  }
  if (gi == 0) {
    float inv = 1.f / l;
    const float4* b4 = (const float4*)bias;
    float4* ob = (float4*)out;
    #pragma unroll
    for (int k = 0; k < 4; ++k) {
      float4 bb = b4[4 * sub + k];
      float4 o;
      o.x = acc[4 * k + 0] * inv + bb.x;
      o.y = acc[4 * k + 1] * inv + bb.y;
      o.z = acc[4 * k + 2] * inv + bb.z;
      o.w = acc[4 * k + 3] * inv + bb.w;
      ob[(size_t)n * 32 + 4 * sub + k] = o;
    }
  }
}

extern "C" void kernel_launch(void* const* d_in, const int* in_sizes, int n_in,
                              void* d_out, int out_size, void* d_ws, size_t ws_size,
                              hipStream_t stream) {
  const float* x    = (const float*)d_in[0];
  const int*   ei   = (const int*)d_in[1];
  const float* Wl1  = (const float*)d_in[2];
  const float* Wr1  = (const float*)d_in[3];
  const float* att1 = (const float*)d_in[4];
  const float* b1   = (const float*)d_in[5];
  const float* bn1g = (const float*)d_in[6];
  const float* bn1b = (const float*)d_in[7];
  const float* bn1m = (const float*)d_in[8];
  const float* bn1v = (const float*)d_in[9];
  const float* Wl2  = (const float*)d_in[10];
  const float* Wr2  = (const float*)d_in[11];
  const float* att2 = (const float*)d_in[12];
  const float* b2   = (const float*)d_in[13];
  const float* bn2g = (const float*)d_in[14];
  const float* bn2b = (const float*)d_in[15];
  const float* bn2m = (const float*)d_in[16];
  const float* bn2v = (const float*)d_in[17];
  const float* Wl3  = (const float*)d_in[18];
  const float* Wr3  = (const float*)d_in[19];
  const float* att3 = (const float*)d_in[20];
  const float* b3   = (const float*)d_in[21];

  const int Hm   = in_sizes[5];          // 256
  const int Cout = in_sizes[21];         // 128
  const int Cin  = in_sizes[2] / Hm;     // 128
  const int N    = in_sizes[0] / Cin;    // 50000
  const int E    = in_sizes[1] / 2;      // 800000
  const int T    = E + N;

  _Float16* x16 = (_Float16*)d_ws;                 // N*Cin
  _Float16* h   = x16 + (size_t)N * Cin;           // N*Hm
  _Float16* xlr = h + (size_t)N * Hm;              // N*2*Hm
  _Float16* WT1 = xlr + (size_t)N * 2 * Hm;        // (2*Hm)*Cin
  _Float16* WT2 = WT1 + (size_t)2 * Hm * Cin;      // (2*Hm)*Hm
  _Float16* WT3 = WT2 + (size_t)2 * Hm * Hm;       // (2*Cout)*Hm
  _Float16* a16_1 = WT3 + (size_t)2 * Cout * Hm;   // 256
  _Float16* a16_2 = a16_1 + 256;                   // 256
  _Float16* a16_3 = a16_2 + 256;                   // 128
  float* sc1 = (float*)(a16_3 + 128);              // 256
  float* sh1 = sc1 + 256;
  float* sc2 = sh1 + 256;
  float* sh2 = sc2 + 256;
  int* deg    = (int*)(sh2 + 256);                 // N
  int* offs   = deg + N;                           // N+1
  int* cursor = offs + N + 1;                      // N
  int* csr    = cursor + N;                        // T+32 (sentinels)
  int* bsum   = csr + T + 32;

  const int nb = (N + 255) / 256;

  // --- CSR build by dst (hierarchical scan) ---
  k_zero_i32<<<(N + 255) / 256, 256, 0, stream>>>(deg, N);
  k_count<<<(T + 255) / 256, 256, 0, stream>>>(ei, E, N, deg);
  k_bsum<<<nb, 256, 0, stream>>>(deg, N, bsum);
  k_bscan<<<1, 1024, 0, stream>>>(bsum, nb, N, offs);
  k_boffs<<<nb, 256, 0, stream>>>(deg, N, bsum, offs, cursor);
  k_scatter<<<(T + 255) / 256, 256, 0, stream>>>(ei, E, N, cursor, csr);

  // --- convert inputs to fp16 / fold constants ---
  int n2 = N * Cin / 2;
  k_f2h<<<(n2 + 255) / 256, 256, 0, stream>>>(x, (unsigned int*)x16, n2);
  int wtot = 2 * Hm * Cin + 2 * Hm * Hm + 2 * Cout * Hm;
  k_prep_w3<<<(wtot + 255) / 256, 256, 0, stream>>>(Wl1, Wr1, Wl2, Wr2, Wl3, Wr3,
                                                    Cin, Hm, Cout, WT1, WT2, WT3);
  k_prep_misc<<<1, 256, 0, stream>>>(att1, att2, att3,
                                     b1, bn1g, bn1b, bn1m, bn1v,
                                     b2, bn2g, bn2b, bn2m, bn2v,
                                     a16_1, a16_2, a16_3, sc1, sh1, sc2, sh2);

  const int mb = (N + 127) / 128;
  const int gb = (N + 3) / 4;

  // --- layer 1 ---
  k_hgemm<<<dim3(mb, 2 * Hm / 256), 512, 0, stream>>>(x16, WT1, xlr, N, 2 * Hm, Cin);
  k_gat4<<<gb, 256, 0, stream>>>(xlr, a16_1, sc1, sh1, offs, csr, N, h);

  // --- layer 2 ---
  k_hgemm<<<dim3(mb, 2 * Hm / 256), 512, 0, stream>>>(h, WT2, xlr, N, 2 * Hm, Hm);
  k_gat4<<<gb, 256, 0, stream>>>(xlr, a16_2, sc2, sh2, offs, csr, N, h);

  // --- layer 3 ---
  k_hgemm<<<dim3(mb, 2 * Cout / 256), 512, 0, stream>>>(h, WT3, xlr, N, 2 * Cout, Hm);
  k_gat1<<<gb, 256, 0, stream>>>(xlr, a16_3, b3, offs, csr, N, (float*)d_out);
}